// Round 3
// 1310.422 us; speedup vs baseline: 1.1033x; 1.1033x over previous
//
#include <hip/hip_runtime.h>
#include <math.h>

#define H      1024
#define B      128
#define T      256
#define GROUPS 8        // 8 groups x 32 blocks = 256 blocks (1/CU target)
#define BPG    32       // blocks per group; block owns 32 dims = 128 gate rows
#define NTHR   512
#define MPG    16       // batches per group
#define DPB    32       // dims per block
#define GRP_SHORTS (MPG * H)   // 16384 shorts = 32 KB per group per parity

typedef __attribute__((ext_vector_type(8))) short  bf16x8;
typedef __attribute__((ext_vector_type(4))) float  floatx4;
typedef __attribute__((ext_vector_type(4))) int    int4v;

static __device__ __forceinline__ unsigned short bf16_rne(float f) {
    unsigned int u = __float_as_uint(f);
    u += 0x7FFF + ((u >> 16) & 1);
    return (unsigned short)(u >> 16);
}
static __device__ __forceinline__ float sigmoidf_(float x) { return 1.0f / (1.0f + __expf(-x)); }

// write-through stores: land at the device coherence point, leave no dirty L2
// line behind => no buffer_wbl2 needed anywhere in the loop (R0-proven).
static __device__ __forceinline__ void store16_wt(void* p, int4v v) {
    asm volatile("global_store_dwordx4 %0, %1, off sc0 sc1" :: "v"(p), "v"(v) : "memory");
}
static __device__ __forceinline__ void store4_wt(void* p, float v) {
    asm volatile("global_store_dword %0, %1, off sc0 sc1" :: "v"(p), "v"(v) : "memory");
}
// coherence-point loads (bypass L1+L2): always fresh, no acquire-inv needed.
// No internal waitcnt — fenced later with register-tied asm.
static __device__ __forceinline__ int4v load16_nc(const void* p) {
    int4v v;
    asm volatile("global_load_dwordx4 %0, %1, off sc0 sc1" : "=v"(v) : "v"(p) : "memory");
    return v;
}
static __device__ __forceinline__ float load4_nc(const void* p) {
    float v;
    asm volatile("global_load_dword %0, %1, off sc0 sc1" : "=v"(v) : "v"(p) : "memory");
    return v;
}
static __device__ __forceinline__ float load4_ncw(const void* p) {
    float v;
    asm volatile("global_load_dword %0, %1, off sc0 sc1\n\ts_waitcnt vmcnt(0)"
                 : "=v"(v) : "v"(p) : "memory");
    return v;
}

// Persistent LSTM decoder. 8 groups x 32 blocks (static grouping). Group g owns
// batches [16g,16g+16); block rb owns dims [32rb,32rb+32) => 128 gate rows
// (8 n-tiles). W' = W_hh + W_ih[:,0](x)W_lin, hi-bf16, in registers. Wave w
// owns K-eighth [128w,128w+128) and ALL 8 n-tiles => h loads go straight
// global->VGPR.
//
// R3 protocol change vs R0 (same stores/flags/gens, restructured waiting):
//  - PER-WAVE polling: wave w polls only its 4 producer blocks (4w..4w+3)
//    right before its own h loads. Wave 1 polls all 32 (it consumes the pbuf
//    partials of every peer). Block-wide "all peers arrived" still holds at
//    the post-MFMA __syncthreads (8 waves x 4 = 32), so overwrite safety is
//    identical to the full-barrier protocol.
//  - pbuf partials read via sc0 sc1 bypass loads => the per-step ACQUIRE
//    (buffer_inv) is gone. Nothing else depended on it (h loads already
//    bypass; flags are device-scope atomics; the rest is LDS/registers).
//  - post-phase-D __syncthreads removed (2 barriers/step instead of 3).
__global__ __launch_bounds__(NTHR, 2) void decoder_kernel(
    const float* __restrict__ hidden0, const float* __restrict__ cell0,
    const float* __restrict__ Wih,     const float* __restrict__ Whh,
    const float* __restrict__ bih,     const float* __restrict__ bhh,
    const float* __restrict__ Wlin,    const float* __restrict__ blin,
    float* __restrict__ out,           float* __restrict__ ws)
{
    __shared__ float Dlds[8][8][MPG][18];         // 73.7 KB: [kh8][ntile][m][n+pad]
    __shared__ float s0_lds[MPG];
    __shared__ float postage[MPG];
    __shared__ __align__(16) unsigned short hstage[512];   // 1 KB, chunk layout

    const int blk  = blockIdx.x;
    const int g    = blk >> 5;          // group 0..7
    const int rb   = blk & 31;          // block in group 0..31
    const int tid  = threadIdx.x;
    const int lane = tid & 63;
    const int wave = tid >> 6;          // 8 waves: wave = K-eighth
    const int l15  = lane & 15;
    const int q    = lane >> 4;

    // ws: flags 8 groups x 64 uints (256 B apart) | hbuf 512 KB | pbuf 32 KB
    unsigned int*   flags = (unsigned int*)ws + g * 64;            // 32 used
    unsigned short* hbuf  = (unsigned short*)((char*)ws + 4096);   // [2][G][GRP_SHORTS]
    float*          pbuf  = (float*)((char*)ws + 4096 + 2 * GROUPS * GRP_SHORTS * 2); // [2][G][MPG][BPG]

    // each wave polls its 4 h-producers; wave1 polls all 32 (pbuf consumers)
    const int fidx = (wave == 1) ? (lane & 31) : (wave * 4 + (lane & 3));

    // ---- W' hi-bf16 B-fragments in registers: 8 n-tiles x K/8 = 32 frags ----
    bf16x8 w_hi[8][4];
    #pragma unroll
    for (int ntl = 0; ntl < 8; ++ntl) {
        const int gate = ntl >> 1;
        const int row  = gate * H + rb * DPB + (ntl & 1) * 16 + l15;
        const float* wrow  = Whh + (size_t)row * H;
        const float  wih0r = Wih[row * 2];
        #pragma unroll
        for (int kt = 0; kt < 4; ++kt) {
            const int k0 = wave * 128 + kt * 32 + q * 8;
            #pragma unroll
            for (int j = 0; j < 8; ++j) {
                float w = wrow[k0 + j] + wih0r * Wlin[k0 + j];
                w_hi[ntl][kt][j] = (short)bf16_rne(w);
            }
        }
    }

    // ---- pointwise-thread constants: thread (pm, pj) ----
    const int pm    = tid >> 5;               // batch in group 0..15
    const int pj    = tid & 31;               // dim within block 0..31
    const int bglob = g * MPG + pm;
    const int kdim  = rb * DPB + pj;
    const float bl  = blin[0];
    float bias_p[4], bias0_p[4], wih0_p[4];
    #pragma unroll
    for (int gt = 0; gt < 4; ++gt) {
        int r2 = gt * H + kdim;
        float b0 = bih[r2] + bhh[r2];
        float w0 = Wih[r2 * 2];
        bias0_p[gt] = b0;
        wih0_p[gt]  = w0;
        bias_p[gt]  = b0 + Wih[r2 * 2 + 1] + w0 * bl;   // folded bias (t>=1)
    }
    float cstate = cell0[(size_t)bglob * H + kdim];
    const float wlin_p = Wlin[kdim];

    // ---- s0[m] = Wlin . h0[m]  (t=0 rank-1 correction) ----
    {
        const float* hp = hidden0 + (size_t)bglob * H + pj * 32;
        const float* wp = Wlin + pj * 32;
        float s = 0.f;
        #pragma unroll 4
        for (int kk = 0; kk < 32; kk += 4) {
            float4 hv = *(const float4*)(hp + kk);
            float4 wv = *(const float4*)(wp + kk);
            s += hv.x * wv.x + hv.y * wv.y + hv.z * wv.z + hv.w * wv.w;
        }
        s += __shfl_xor(s, 1); s += __shfl_xor(s, 2);
        s += __shfl_xor(s, 4); s += __shfl_xor(s, 8); s += __shfl_xor(s, 16);
        if (pj == 0) s0_lds[pm] = s;
    }

    // ---- preamble: h0 -> hstage (chunk layout) -> wave0 WT store + flag ----
    {
        float v0 = hidden0[(size_t)bglob * H + kdim];
        hstage[(pj >> 3) * 128 + pm * 8 + (pj & 7)] = bf16_rne(v0);
    }
    __syncthreads();
    if (wave == 0) {
        int4v hv = *(const int4v*)(hstage + lane * 8);
        store16_wt(hbuf + (size_t)(0 * GROUPS + g) * GRP_SHORTS + rb * 512 + lane * 8, hv);
        asm volatile("s_waitcnt vmcnt(0)" ::: "memory");
        if (lane == 0)
            __hip_atomic_store(&flags[rb], 1u, __ATOMIC_RELAXED, __HIP_MEMORY_SCOPE_AGENT);
    }
    // no preamble poll: each wave polls its producers at the top of step 0.
    // hstage is next written in phase C(0), which is after the post-MFMA
    // __syncthreads, which waits for wave0 -> no LDS hazard.

    for (int t = 0; t < T; ++t) {
        // ---- per-wave producer poll: h parity t&1 published with gen t+1 ----
        {
            const unsigned int gen = (unsigned int)(t + 1);
            for (;;) {
                unsigned int v = __hip_atomic_load(&flags[fidx], __ATOMIC_RELAXED,
                                                   __HIP_MEMORY_SCOPE_AGENT);
                if (__all((int)(v >= gen))) break;
            }
        }

        // ---- phase A: direct h_t loads (this wave's 4 chunks) -> VGPRs ----
        const char* hsrc = (const char*)(hbuf + (size_t)((t & 1) * GROUPS + g) * GRP_SHORTS)
                         + wave * 4096 + lane * 16;
        int4v a0 = load16_nc(hsrc);
        int4v a1 = load16_nc(hsrc + 1024);
        int4v a2 = load16_nc(hsrc + 2048);
        int4v a3 = load16_nc(hsrc + 3072);
        float pv = 0.f;
        if (wave == 1 && rb < MPG && t > 0) {
            // batch m = rb: 32 block-partials written at step t-1 (parity (t-1)&1),
            // guarded by this wave's all-32 poll at gen t+1; bypass loads = fresh.
            const float* pr = pbuf + (size_t)((((t - 1) & 1) * GROUPS + g) * MPG + rb) * BPG;
            pv = load4_nc(pr + (lane & 31));
        }
        // fence: ties the loaded regs so MFMA cannot be scheduled before drain
        asm volatile("s_waitcnt vmcnt(0)"
                     : "+v"(a0), "+v"(a1), "+v"(a2), "+v"(a3), "+v"(pv));
        if (wave == 1 && rb < MPG && t > 0) {
            float v = pv;
            v += __shfl_xor(v, 1); v += __shfl_xor(v, 2); v += __shfl_xor(v, 4);
            v += __shfl_xor(v, 8); v += __shfl_xor(v, 16);
            if (lane == 0) out[(size_t)(g * MPG + rb) * T + (t - 1)] = v + bl;
        }

        // ---- phase B: MFMA. wave w: 8 n-tiles x 16 batches x K/8 ----
        bf16x8 a[4];
        a[0] = __builtin_bit_cast(bf16x8, a0);
        a[1] = __builtin_bit_cast(bf16x8, a1);
        a[2] = __builtin_bit_cast(bf16x8, a2);
        a[3] = __builtin_bit_cast(bf16x8, a3);
        floatx4 acc[8];
        #pragma unroll
        for (int ntl = 0; ntl < 8; ++ntl) acc[ntl] = (floatx4){0.f, 0.f, 0.f, 0.f};
        #pragma unroll
        for (int kt = 0; kt < 4; ++kt) {
            #pragma unroll
            for (int ntl = 0; ntl < 8; ++ntl)
                acc[ntl] = __builtin_amdgcn_mfma_f32_16x16x32_bf16(a[kt], w_hi[ntl][kt], acc[ntl], 0, 0, 0);
        }
        #pragma unroll
        for (int ntl = 0; ntl < 8; ++ntl) {     // C/D: col=lane&15, row=q*4+r
            #pragma unroll
            for (int r = 0; r < 4; ++r)
                Dlds[wave][ntl][q * 4 + r][l15] = acc[ntl][r];
        }
        __syncthreads();   // post-B: all Dlds slices written; all polls merged

        // ---- phase C: pointwise (thread (pm, pj)) -> LDS stash ----
        {
            const int nt0 = pj >> 4, nn = pj & 15;
            float gv[4];
            #pragma unroll
            for (int gt = 0; gt < 4; ++gt) {
                const int nt = gt * 2 + nt0;
                float s = 0.f;
                #pragma unroll
                for (int kk = 0; kk < 8; ++kk)
                    s += Dlds[kk][nt][pm][nn];
                gv[gt] = s;
            }
            if (t == 0) {
                float s0 = s0_lds[pm];
                #pragma unroll
                for (int gt = 0; gt < 4; ++gt) gv[gt] += bias0_p[gt] - wih0_p[gt] * s0;
            } else {
                #pragma unroll
                for (int gt = 0; gt < 4; ++gt) gv[gt] += bias_p[gt];
            }
            float ig  = sigmoidf_(gv[0]);
            float fg  = sigmoidf_(gv[1]);
            float gt_ = tanhf(gv[2]);
            float og  = sigmoidf_(gv[3]);
            cstate = fg * cstate + ig * gt_;
            float hnew = og * tanhf(cstate);

            hstage[(pj >> 3) * 128 + pm * 8 + (pj & 7)] = bf16_rne(hnew);
            float po = wlin_p * hnew;
            po += __shfl_xor(po, 1); po += __shfl_xor(po, 2);
            po += __shfl_xor(po, 4); po += __shfl_xor(po, 8); po += __shfl_xor(po, 16);
            if (pj == 0) postage[pm] = po;
        }
        __syncthreads();   // post-C: hstage/postage complete for wave0's store

        // ---- phase D: wave0 store + drain + arrive (no block barrier after) ----
        if (wave == 0) {
            const unsigned int gen = (unsigned int)(t + 2);
            int4v hv = *(const int4v*)(hstage + lane * 8);
            store16_wt(hbuf + (size_t)(((t + 1) & 1) * GROUPS + g) * GRP_SHORTS
                       + rb * 512 + lane * 8, hv);
            if (lane < MPG)
                store4_wt(pbuf + (size_t)(((t & 1) * GROUPS + g) * MPG + lane) * BPG + rb,
                          postage[lane]);
            asm volatile("s_waitcnt vmcnt(0)" ::: "memory");   // drain wave0's WT stores
            if (lane == 0)
                __hip_atomic_store(&flags[rb], gen, __ATOMIC_RELAXED, __HIP_MEMORY_SCOPE_AGENT);
        }
        // waves flow directly into step t+1's per-wave poll
    }

    // ---- epilogue: output column t = T-1 (pbuf parity (T-1)&1, gen T+1) ----
    if (wave == 1 && rb < MPG) {
        {
            const unsigned int gen = (unsigned int)(T + 1);
            for (;;) {
                unsigned int v = __hip_atomic_load(&flags[lane & 31], __ATOMIC_RELAXED,
                                                   __HIP_MEMORY_SCOPE_AGENT);
                if (__all((int)(v >= gen))) break;
            }
        }
        const float* pr = pbuf + (size_t)((((T - 1) & 1) * GROUPS + g) * MPG + rb) * BPG;
        float v = load4_ncw(pr + (lane & 31));
        v += __shfl_xor(v, 1); v += __shfl_xor(v, 2); v += __shfl_xor(v, 4);
        v += __shfl_xor(v, 8); v += __shfl_xor(v, 16);
        if (lane == 0) out[(size_t)(g * MPG + rb) * T + (T - 1)] = v + bl;
    }
}

extern "C" void kernel_launch(void* const* d_in, const int* in_sizes, int n_in,
                              void* d_out, int out_size, void* d_ws, size_t ws_size,
                              hipStream_t stream) {
    const float* hidden0 = (const float*)d_in[0];
    const float* cell0   = (const float*)d_in[1];
    const float* Wih     = (const float*)d_in[2];
    const float* Whh     = (const float*)d_in[3];
    const float* bih     = (const float*)d_in[4];
    const float* bhh     = (const float*)d_in[5];
    const float* Wlin    = (const float*)d_in[6];
    const float* blin    = (const float*)d_in[7];
    float* out = (float*)d_out;
    float* ws  = (float*)d_ws;

    // zero the barrier flags
    hipMemsetAsync(d_ws, 0, 4096, stream);

    void* args[] = { &hidden0, &cell0, &Wih, &Whh, &bih, &bhh, &Wlin, &blin,
                     &out, &ws };
    hipLaunchCooperativeKernel((const void*)decoder_kernel,
                               dim3(GROUPS * BPG), dim3(NTHR), args, 0, stream);
}

// Round 4
// 1196.304 us; speedup vs baseline: 1.2086x; 1.0954x over previous
//
#include <hip/hip_runtime.h>
#include <math.h>

#define H      1024
#define B      128
#define T      256
#define GROUPS 8        // 8 groups x 32 blocks = 256 blocks (1/CU target)
#define BPG    32       // blocks per group; block owns 32 dims = 128 gate rows
#define NTHR   512
#define MPG    16       // batches per group
#define DPB    32       // dims per block
#define GRP_SHORTS (MPG * H)   // 16384 shorts = 32 KB per group per parity

typedef __attribute__((ext_vector_type(8))) short  bf16x8;
typedef __attribute__((ext_vector_type(4))) float  floatx4;
typedef __attribute__((ext_vector_type(4))) int    int4v;

static __device__ __forceinline__ unsigned short bf16_rne(float f) {
    unsigned int u = __float_as_uint(f);
    u += 0x7FFF + ((u >> 16) & 1);
    return (unsigned short)(u >> 16);
}
static __device__ __forceinline__ float sigmoidf_(float x) { return 1.0f / (1.0f + __expf(-x)); }

// write-through stores: land at the device coherence point, leave no dirty L2
// line behind => no buffer_wbl2 needed anywhere in the loop (R0-proven).
static __device__ __forceinline__ void store16_wt(void* p, int4v v) {
    asm volatile("global_store_dwordx4 %0, %1, off sc0 sc1" :: "v"(p), "v"(v) : "memory");
}
static __device__ __forceinline__ void store4_wt(void* p, float v) {
    asm volatile("global_store_dword %0, %1, off sc0 sc1" :: "v"(p), "v"(v) : "memory");
}
static __device__ __forceinline__ void store2_wt(void* p, unsigned int v) {
    asm volatile("global_store_short %0, %1, off sc0 sc1" :: "v"(p), "v"(v) : "memory");
}
// coherence-point loads (bypass L1+L2): always fresh, no acquire-inv needed.
// No internal waitcnt — fenced later with register-tied asm.
static __device__ __forceinline__ int4v load16_nc(const void* p) {
    int4v v;
    asm volatile("global_load_dwordx4 %0, %1, off sc0 sc1" : "=v"(v) : "v"(p) : "memory");
    return v;
}
static __device__ __forceinline__ float load4_nc(const void* p) {
    float v;
    asm volatile("global_load_dword %0, %1, off sc0 sc1" : "=v"(v) : "v"(p) : "memory");
    return v;
}
static __device__ __forceinline__ float load4_ncw(const void* p) {
    float v;
    asm volatile("global_load_dword %0, %1, off sc0 sc1\n\ts_waitcnt vmcnt(0)"
                 : "=v"(v) : "v"(p) : "memory");
    return v;
}

// Persistent LSTM decoder. 8 groups x 32 blocks (static grouping). Group g owns
// batches [16g,16g+16); block rb owns dims [32rb,32rb+32) => 128 gate rows
// (8 n-tiles). W' = W_hh + W_ih[:,0](x)W_lin, hi-bf16, in registers. Wave w
// owns K-eighth [128w,128w+128) and ALL 8 n-tiles => h loads go straight
// global->VGPR.
//
// R4 protocol changes vs R3:
//  - DISTRIBUTED PUBLISH: every thread stores its own bf16 h value (2B WT)
//    during phase C; each wave drains its own stores before the post-C
//    barrier (8 concurrent drains instead of wave0's serial restage+drain);
//    tid0 fires the flag right after the barrier (fire-and-forget). Phase D
//    is gone — no wave enters the next step late.
//  - pbuf is a DEPTH-4 RING consumed at LAG 3: wave1 at step t reduces step
//    t-3's partials with NO polling (post-B of step t-1 merged all-32 polls
//    at gen >= t, which certifies all peers drained their step t-2 pbuf
//    stores, hence step t-3's as well). Every wave polls only its 4
//    h-producers; the all-32 gather exists only in the epilogue.
//  - Anti-overwrite (h): write of parity (t+1)&1 in phase C of step t is
//    after post-B of step t = merged all-32 @ gen>=t+1 = all peers finished
//    their phase-A reads of that parity (step t-1). Same argument as R3.
//  - Anti-overwrite (pbuf ring): slot s&3 rewritten at step s+4, after
//    post-B of s+4 = all-32 @ gen>=s+5 = peers finished phase C of step s+3,
//    i.e. after their wave1 read of slot s&3 at step s+3.
__global__ __launch_bounds__(NTHR, 2) void decoder_kernel(
    const float* __restrict__ hidden0, const float* __restrict__ cell0,
    const float* __restrict__ Wih,     const float* __restrict__ Whh,
    const float* __restrict__ bih,     const float* __restrict__ bhh,
    const float* __restrict__ Wlin,    const float* __restrict__ blin,
    float* __restrict__ out,           float* __restrict__ ws)
{
    __shared__ float Dlds[8][8][MPG][18];         // 73.7 KB: [kh8][ntile][m][n+pad]
    __shared__ float s0_lds[MPG];
    __shared__ __align__(16) unsigned short hstage[512];   // 1 KB, preamble only

    const int blk  = blockIdx.x;
    const int g    = blk >> 5;          // group 0..7
    const int rb   = blk & 31;          // block in group 0..31
    const int tid  = threadIdx.x;
    const int lane = tid & 63;
    const int wave = tid >> 6;          // 8 waves: wave = K-eighth
    const int l15  = lane & 15;
    const int q    = lane >> 4;

    // ws: flags 8 groups x 64 uints | hbuf 512 KB | pbuf ring 64 KB
    unsigned int*   flags = (unsigned int*)ws + g * 64;            // 32 used
    unsigned short* hbuf  = (unsigned short*)((char*)ws + 4096);   // [2][G][GRP_SHORTS]
    float*          pbuf  = (float*)((char*)ws + 4096 + 2 * GROUPS * GRP_SHORTS * 2); // [4][G][MPG][BPG]

    // every wave polls its 4 h-producer blocks (union over 8 waves = all 32)
    const int fidx = wave * 4 + (lane & 3);

    // ---- W' hi-bf16 B-fragments in registers: 8 n-tiles x K/8 = 32 frags ----
    bf16x8 w_hi[8][4];
    #pragma unroll
    for (int ntl = 0; ntl < 8; ++ntl) {
        const int gate = ntl >> 1;
        const int row  = gate * H + rb * DPB + (ntl & 1) * 16 + l15;
        const float* wrow  = Whh + (size_t)row * H;
        const float  wih0r = Wih[row * 2];
        #pragma unroll
        for (int kt = 0; kt < 4; ++kt) {
            const int k0 = wave * 128 + kt * 32 + q * 8;
            #pragma unroll
            for (int j = 0; j < 8; ++j) {
                float w = wrow[k0 + j] + wih0r * Wlin[k0 + j];
                w_hi[ntl][kt][j] = (short)bf16_rne(w);
            }
        }
    }

    // ---- pointwise-thread constants: thread (pm, pj) ----
    const int pm    = tid >> 5;               // batch in group 0..15
    const int pj    = tid & 31;               // dim within block 0..31
    const int bglob = g * MPG + pm;
    const int kdim  = rb * DPB + pj;
    const float bl  = blin[0];
    float bias_p[4], bias0_p[4], wih0_p[4];
    #pragma unroll
    for (int gt = 0; gt < 4; ++gt) {
        int r2 = gt * H + kdim;
        float b0 = bih[r2] + bhh[r2];
        float w0 = Wih[r2 * 2];
        bias0_p[gt] = b0;
        wih0_p[gt]  = w0;
        bias_p[gt]  = b0 + Wih[r2 * 2 + 1] + w0 * bl;   // folded bias (t>=1)
    }
    float cstate = cell0[(size_t)bglob * H + kdim];
    const float wlin_p = Wlin[kdim];

    // per-thread h-publish addresses (chunk layout), one per parity
    const size_t hoff = (size_t)rb * 512 + (pj >> 3) * 128 + pm * 8 + (pj & 7);
    unsigned short* hdst0 = hbuf + (size_t)(0 * GROUPS + g) * GRP_SHORTS + hoff;
    unsigned short* hdst1 = hbuf + (size_t)(1 * GROUPS + g) * GRP_SHORTS + hoff;

    // ---- s0[m] = Wlin . h0[m]  (t=0 rank-1 correction) ----
    {
        const float* hp = hidden0 + (size_t)bglob * H + pj * 32;
        const float* wp = Wlin + pj * 32;
        float s = 0.f;
        #pragma unroll 4
        for (int kk = 0; kk < 32; kk += 4) {
            float4 hv = *(const float4*)(hp + kk);
            float4 wv = *(const float4*)(wp + kk);
            s += hv.x * wv.x + hv.y * wv.y + hv.z * wv.z + hv.w * wv.w;
        }
        s += __shfl_xor(s, 1); s += __shfl_xor(s, 2);
        s += __shfl_xor(s, 4); s += __shfl_xor(s, 8); s += __shfl_xor(s, 16);
        if (pj == 0) s0_lds[pm] = s;
    }

    // ---- preamble: h0 -> hstage (chunk layout) -> wave0 WT store + flag ----
    {
        float v0 = hidden0[(size_t)bglob * H + kdim];
        hstage[(pj >> 3) * 128 + pm * 8 + (pj & 7)] = bf16_rne(v0);
    }
    __syncthreads();
    if (wave == 0) {
        int4v hv = *(const int4v*)(hstage + lane * 8);
        store16_wt(hbuf + (size_t)(0 * GROUPS + g) * GRP_SHORTS + rb * 512 + lane * 8, hv);
        asm volatile("s_waitcnt vmcnt(0)" ::: "memory");
        if (lane == 0)
            __hip_atomic_store(&flags[rb], 1u, __ATOMIC_RELAXED, __HIP_MEMORY_SCOPE_AGENT);
    }
    // other waves flow straight into step 0's poll (gen 1)

    for (int t = 0; t < T; ++t) {
        // ---- per-wave producer poll: h parity t&1 published with gen t+1 ----
        {
            const unsigned int gen = (unsigned int)(t + 1);
            for (;;) {
                unsigned int v = __hip_atomic_load(&flags[fidx], __ATOMIC_RELAXED,
                                                   __HIP_MEMORY_SCOPE_AGENT);
                if (__all((int)(v >= gen))) break;
            }
        }

        // ---- phase A: direct h_t loads (this wave's 4 chunks) -> VGPRs ----
        const char* hsrc = (const char*)(hbuf + (size_t)((t & 1) * GROUPS + g) * GRP_SHORTS)
                         + wave * 4096 + lane * 16;
        int4v a0 = load16_nc(hsrc);
        int4v a1 = load16_nc(hsrc + 1024);
        int4v a2 = load16_nc(hsrc + 2048);
        int4v a3 = load16_nc(hsrc + 3072);
        float pv = 0.f;
        if (wave == 1 && rb < MPG && t >= 3) {
            // batch m = rb: step t-3's 32 block-partials (ring slot (t-3)&3).
            // Safety: post-B barrier of step t-1 merged all-32 polls @ gen>=t,
            // certifying every peer drained its step t-2 (hence t-3) pbuf
            // stores; bypass loads are always fresh.
            const float* pr = pbuf + (size_t)((((t - 3) & 3) * GROUPS + g) * MPG + rb) * BPG;
            pv = load4_nc(pr + (lane & 31));
        }
        // fence: ties the loaded regs so MFMA cannot be scheduled before drain
        asm volatile("s_waitcnt vmcnt(0)"
                     : "+v"(a0), "+v"(a1), "+v"(a2), "+v"(a3), "+v"(pv));
        if (wave == 1 && rb < MPG && t >= 3) {
            float v = pv;
            v += __shfl_xor(v, 1); v += __shfl_xor(v, 2); v += __shfl_xor(v, 4);
            v += __shfl_xor(v, 8); v += __shfl_xor(v, 16);
            if (lane == 0) out[(size_t)(g * MPG + rb) * T + (t - 3)] = v + bl;
        }

        // ---- phase B: MFMA. wave w: 8 n-tiles x 16 batches x K/8 ----
        bf16x8 a[4];
        a[0] = __builtin_bit_cast(bf16x8, a0);
        a[1] = __builtin_bit_cast(bf16x8, a1);
        a[2] = __builtin_bit_cast(bf16x8, a2);
        a[3] = __builtin_bit_cast(bf16x8, a3);
        floatx4 acc[8];
        #pragma unroll
        for (int ntl = 0; ntl < 8; ++ntl) acc[ntl] = (floatx4){0.f, 0.f, 0.f, 0.f};
        #pragma unroll
        for (int kt = 0; kt < 4; ++kt) {
            #pragma unroll
            for (int ntl = 0; ntl < 8; ++ntl)
                acc[ntl] = __builtin_amdgcn_mfma_f32_16x16x32_bf16(a[kt], w_hi[ntl][kt], acc[ntl], 0, 0, 0);
        }
        #pragma unroll
        for (int ntl = 0; ntl < 8; ++ntl) {     // C/D: col=lane&15, row=q*4+r
            #pragma unroll
            for (int r = 0; r < 4; ++r)
                Dlds[wave][ntl][q * 4 + r][l15] = acc[ntl][r];
        }
        __syncthreads();   // post-B: Dlds complete; all-32 polls merged block-wide

        // ---- phase C: pointwise + DISTRIBUTED publish (per-thread stores) ----
        {
            const int nt0 = pj >> 4, nn = pj & 15;
            float gv[4];
            #pragma unroll
            for (int gt = 0; gt < 4; ++gt) {
                const int nt = gt * 2 + nt0;
                float s = 0.f;
                #pragma unroll
                for (int kk = 0; kk < 8; ++kk)
                    s += Dlds[kk][nt][pm][nn];
                gv[gt] = s;
            }
            if (t == 0) {
                float s0 = s0_lds[pm];
                #pragma unroll
                for (int gt = 0; gt < 4; ++gt) gv[gt] += bias0_p[gt] - wih0_p[gt] * s0;
            } else {
                #pragma unroll
                for (int gt = 0; gt < 4; ++gt) gv[gt] += bias_p[gt];
            }
            float ig  = sigmoidf_(gv[0]);
            float fg  = sigmoidf_(gv[1]);
            float gt_ = tanhf(gv[2]);
            float og  = sigmoidf_(gv[3]);
            cstate = fg * cstate + ig * gt_;
            float hnew = og * tanhf(cstate);

            // h publish: this thread's bf16 into parity (t+1)&1, issued early
            // so its latency overlaps the rest of phase C
            store2_wt(((t + 1) & 1) ? (void*)hdst1 : (void*)hdst0,
                      (unsigned int)bf16_rne(hnew));

            float po = wlin_p * hnew;
            po += __shfl_xor(po, 1); po += __shfl_xor(po, 2);
            po += __shfl_xor(po, 4); po += __shfl_xor(po, 8); po += __shfl_xor(po, 16);
            if (pj == 0)
                store4_wt(pbuf + (size_t)(((t & 3) * GROUPS + g) * MPG + pm) * BPG + rb, po);
        }
        // each wave drains ITS OWN stores; 8 concurrent drains, then merge
        asm volatile("s_waitcnt vmcnt(0)" ::: "memory");
        __syncthreads();   // post-C: all h/pbuf stores committed block-wide

        // arrive: fire-and-forget (consumers' polls absorb the commit latency)
        if (tid == 0)
            __hip_atomic_store(&flags[rb], (unsigned int)(t + 2),
                               __ATOMIC_RELAXED, __HIP_MEMORY_SCOPE_AGENT);
    }

    // ---- epilogue: output columns T-3, T-2, T-1 (all-32 poll, once) ----
    if (wave == 1 && rb < MPG) {
        {
            const unsigned int gen = (unsigned int)(T + 1);
            for (;;) {
                unsigned int v = __hip_atomic_load(&flags[lane & 31], __ATOMIC_RELAXED,
                                                   __HIP_MEMORY_SCOPE_AGENT);
                if (__all((int)(v >= gen))) break;
            }
        }
        for (int tt = T - 3; tt < T; ++tt) {
            const float* pr = pbuf + (size_t)(((tt & 3) * GROUPS + g) * MPG + rb) * BPG;
            float v = load4_ncw(pr + (lane & 31));
            v += __shfl_xor(v, 1); v += __shfl_xor(v, 2); v += __shfl_xor(v, 4);
            v += __shfl_xor(v, 8); v += __shfl_xor(v, 16);
            if (lane == 0) out[(size_t)(g * MPG + rb) * T + tt] = v + bl;
        }
    }
}

extern "C" void kernel_launch(void* const* d_in, const int* in_sizes, int n_in,
                              void* d_out, int out_size, void* d_ws, size_t ws_size,
                              hipStream_t stream) {
    const float* hidden0 = (const float*)d_in[0];
    const float* cell0   = (const float*)d_in[1];
    const float* Wih     = (const float*)d_in[2];
    const float* Whh     = (const float*)d_in[3];
    const float* bih     = (const float*)d_in[4];
    const float* bhh     = (const float*)d_in[5];
    const float* Wlin    = (const float*)d_in[6];
    const float* blin    = (const float*)d_in[7];
    float* out = (float*)d_out;
    float* ws  = (float*)d_ws;

    // zero the barrier flags
    hipMemsetAsync(d_ws, 0, 4096, stream);

    void* args[] = { &hidden0, &cell0, &Wih, &Whh, &bih, &bhh, &Wlin, &blin,
                     &out, &ws };
    hipLaunchCooperativeKernel((const void*)decoder_kernel,
                               dim3(GROUPS * BPG), dim3(NTHR), args, 0, stream);
}

// Round 5
// 1187.618 us; speedup vs baseline: 1.2174x; 1.0073x over previous
//
#include <hip/hip_runtime.h>
#include <math.h>

#define H      1024
#define B      128
#define T      256
#define GROUPS 8        // 8 groups x 32 blocks = 256 blocks (1/CU target)
#define BPG    32       // blocks per group; block owns 32 dims = 128 gate rows
#define NTHR   512
#define MPG    16       // batches per group
#define DPB    32       // dims per block
#define GRP_SHORTS (MPG * H)   // 16384 shorts = 32 KB per group per parity

typedef __attribute__((ext_vector_type(8))) short  bf16x8;
typedef __attribute__((ext_vector_type(4))) float  floatx4;
typedef __attribute__((ext_vector_type(4))) int    int4v;

static __device__ __forceinline__ unsigned short bf16_rne(float f) {
    unsigned int u = __float_as_uint(f);
    u += 0x7FFF + ((u >> 16) & 1);
    return (unsigned short)(u >> 16);
}
static __device__ __forceinline__ float sigmoidf_(float x) { return 1.0f / (1.0f + __expf(-x)); }

// write-through stores: land at the device coherence point, leave no dirty L2
// line behind => no buffer_wbl2 needed anywhere in the loop (R0-proven).
static __device__ __forceinline__ void store16_wt(void* p, int4v v) {
    asm volatile("global_store_dwordx4 %0, %1, off sc0 sc1" :: "v"(p), "v"(v) : "memory");
}
static __device__ __forceinline__ void store4_wt(void* p, float v) {
    asm volatile("global_store_dword %0, %1, off sc0 sc1" :: "v"(p), "v"(v) : "memory");
}
static __device__ __forceinline__ void store2_wt(void* p, unsigned int v) {
    asm volatile("global_store_short %0, %1, off sc0 sc1" :: "v"(p), "v"(v) : "memory");
}
// coherence-point loads (bypass L1+L2): always fresh, no acquire-inv needed.
// No internal waitcnt — fenced later with register-tied asm.
static __device__ __forceinline__ int4v load16_nc(const void* p) {
    int4v v;
    asm volatile("global_load_dwordx4 %0, %1, off sc0 sc1" : "=v"(v) : "v"(p) : "memory");
    return v;
}
static __device__ __forceinline__ float load4_nc(const void* p) {
    float v;
    asm volatile("global_load_dword %0, %1, off sc0 sc1" : "=v"(v) : "v"(p) : "memory");
    return v;
}
static __device__ __forceinline__ float load4_ncw(const void* p) {
    float v;
    asm volatile("global_load_dword %0, %1, off sc0 sc1\n\ts_waitcnt vmcnt(0)"
                 : "=v"(v) : "v"(p) : "memory");
    return v;
}

// Persistent LSTM decoder. 8 groups x 32 blocks (static grouping). Group g owns
// batches [16g,16g+16); block rb owns dims [32rb,32rb+32) => 128 gate rows
// (8 n-tiles). W' = W_hh + W_ih[:,0](x)W_lin, hi-bf16, in registers. Wave w
// owns K-eighth [128w,128w+128) and ALL 8 n-tiles => h loads go straight
// global->VGPR.
//
// R5 changes vs R4 (protocol IDENTICAL; intra-block data movement only):
//  - Dlds layout [kk][ntl][n][m+pad] (pad 20): MFMA acc (4 batches, same col)
//    stores as ONE ds_write_b128; phase C reads its gate's kk-chain as 8
//    ds_read_b128. 128 LDS wave-instrs/step instead of 512 scalar, and the
//    pad-20 quad-start pattern covers all 32 banks uniformly (32B/bank) on
//    both sides => zero bank conflicts (was 6.7e7 conflict-cycles/dispatch).
//  - 4x4 gate<->batch transpose via 2-stage shfl_xor(16/32): after the b128
//    kk-sum each thread holds gate q for 4 batches; after transpose it holds
//    4 gates for batch bq*4+q. Pointwise thread remap: pm=bq*4+q (q=lane>>4),
//    pj=nhi*16+l15 (nhi=wave&1).
//  - po reduction is now per dim-half (16 lanes): pbuf widens to 64 floats
//    per (slot,batch) = 2 halves x 32 blocks; consumer reduces 64 lanes.
__global__ __launch_bounds__(NTHR, 2) void decoder_kernel(
    const float* __restrict__ hidden0, const float* __restrict__ cell0,
    const float* __restrict__ Wih,     const float* __restrict__ Whh,
    const float* __restrict__ bih,     const float* __restrict__ bhh,
    const float* __restrict__ Wlin,    const float* __restrict__ blin,
    float* __restrict__ out,           float* __restrict__ ws)
{
    __shared__ __align__(16) float Dlds[8][8][16][20];   // 80 KB: [kk][ntl][n][m+pad4]
    __shared__ float s0_lds[MPG];
    __shared__ __align__(16) unsigned short hstage[512];   // 1 KB, preamble only

    const int blk  = blockIdx.x;
    const int g    = blk >> 5;          // group 0..7
    const int rb   = blk & 31;          // block in group 0..31
    const int tid  = threadIdx.x;
    const int lane = tid & 63;
    const int wave = tid >> 6;          // 8 waves: wave = K-eighth
    const int l15  = lane & 15;
    const int q    = lane >> 4;

    // ws: flags 8 groups x 64 uints | hbuf 512 KB | pbuf ring 128 KB
    unsigned int*   flags = (unsigned int*)ws + g * 64;            // 32 used
    unsigned short* hbuf  = (unsigned short*)((char*)ws + 4096);   // [2][G][GRP_SHORTS]
    float*          pbuf  = (float*)((char*)ws + 4096 + 2 * GROUPS * GRP_SHORTS * 2); // [4][G][MPG][64]

    // every wave polls its 4 h-producer blocks (union over 8 waves = all 32)
    const int fidx = wave * 4 + (lane & 3);

    // ---- W' hi-bf16 B-fragments in registers: 8 n-tiles x K/8 = 32 frags ----
    bf16x8 w_hi[8][4];
    #pragma unroll
    for (int ntl = 0; ntl < 8; ++ntl) {
        const int gate = ntl >> 1;
        const int row  = gate * H + rb * DPB + (ntl & 1) * 16 + l15;
        const float* wrow  = Whh + (size_t)row * H;
        const float  wih0r = Wih[row * 2];
        #pragma unroll
        for (int kt = 0; kt < 4; ++kt) {
            const int k0 = wave * 128 + kt * 32 + q * 8;
            #pragma unroll
            for (int j = 0; j < 8; ++j) {
                float w = wrow[k0 + j] + wih0r * Wlin[k0 + j];
                w_hi[ntl][kt][j] = (short)bf16_rne(w);
            }
        }
    }

    // ---- pointwise-thread constants, NEW mapping: pm=bq*4+q, pj=nhi*16+l15 ----
    const int bq    = wave >> 1;              // batch quad 0..3
    const int nhi   = wave & 1;               // dim half 0..1
    const int pm    = bq * 4 + q;             // batch in group 0..15
    const int pj    = nhi * 16 + l15;         // dim within block 0..31
    const int bglob = g * MPG + pm;
    const int kdim  = rb * DPB + pj;
    const float bl  = blin[0];
    float bias_p[4], bias0_p[4], wih0_p[4];
    #pragma unroll
    for (int gt = 0; gt < 4; ++gt) {
        int r2 = gt * H + kdim;
        float b0 = bih[r2] + bhh[r2];
        float w0 = Wih[r2 * 2];
        bias0_p[gt] = b0;
        wih0_p[gt]  = w0;
        bias_p[gt]  = b0 + Wih[r2 * 2 + 1] + w0 * bl;   // folded bias (t>=1)
    }
    float cstate = cell0[(size_t)bglob * H + kdim];
    const float wlin_p = Wlin[kdim];

    // per-thread h-publish addresses (chunk layout), one per parity
    const size_t hoff = (size_t)rb * 512 + (pj >> 3) * 128 + pm * 8 + (pj & 7);
    unsigned short* hdst0 = hbuf + (size_t)(0 * GROUPS + g) * GRP_SHORTS + hoff;
    unsigned short* hdst1 = hbuf + (size_t)(1 * GROUPS + g) * GRP_SHORTS + hoff;

    // ---- preamble (OLD mapping pm_o/pj_o): s0 + h0 stage ----
    {
        const int pm_o = tid >> 5, pj_o = tid & 31;
        // s0[m] = Wlin . h0[m]  (t=0 rank-1 correction)
        const float* hp = hidden0 + (size_t)(g * MPG + pm_o) * H + pj_o * 32;
        const float* wp = Wlin + pj_o * 32;
        float s = 0.f;
        #pragma unroll 4
        for (int kk = 0; kk < 32; kk += 4) {
            float4 hv = *(const float4*)(hp + kk);
            float4 wv = *(const float4*)(wp + kk);
            s += hv.x * wv.x + hv.y * wv.y + hv.z * wv.z + hv.w * wv.w;
        }
        s += __shfl_xor(s, 1); s += __shfl_xor(s, 2);
        s += __shfl_xor(s, 4); s += __shfl_xor(s, 8); s += __shfl_xor(s, 16);
        if (pj_o == 0) s0_lds[pm_o] = s;

        float v0 = hidden0[(size_t)(g * MPG + pm_o) * H + rb * DPB + pj_o];
        hstage[(pj_o >> 3) * 128 + pm_o * 8 + (pj_o & 7)] = bf16_rne(v0);
    }
    __syncthreads();
    if (wave == 0) {
        int4v hv = *(const int4v*)(hstage + lane * 8);
        store16_wt(hbuf + (size_t)(0 * GROUPS + g) * GRP_SHORTS + rb * 512 + lane * 8, hv);
        asm volatile("s_waitcnt vmcnt(0)" ::: "memory");
        if (lane == 0)
            __hip_atomic_store(&flags[rb], 1u, __ATOMIC_RELAXED, __HIP_MEMORY_SCOPE_AGENT);
    }
    // other waves flow straight into step 0's poll (gen 1)

    for (int t = 0; t < T; ++t) {
        // ---- per-wave producer poll: h parity t&1 published with gen t+1 ----
        {
            const unsigned int gen = (unsigned int)(t + 1);
            for (;;) {
                unsigned int v = __hip_atomic_load(&flags[fidx], __ATOMIC_RELAXED,
                                                   __HIP_MEMORY_SCOPE_AGENT);
                if (__all((int)(v >= gen))) break;
            }
        }

        // ---- phase A: direct h_t loads (this wave's 4 chunks) -> VGPRs ----
        const char* hsrc = (const char*)(hbuf + (size_t)((t & 1) * GROUPS + g) * GRP_SHORTS)
                         + wave * 4096 + lane * 16;
        int4v a0 = load16_nc(hsrc);
        int4v a1 = load16_nc(hsrc + 1024);
        int4v a2 = load16_nc(hsrc + 2048);
        int4v a3 = load16_nc(hsrc + 3072);
        float pv = 0.f;
        if (wave == 1 && rb < MPG && t >= 3) {
            // batch m = rb: step t-3's 64 partials (2 halves x 32 blocks).
            // Safety: post-B barrier of step t-1 merged all-32 polls @ gen>=t.
            const float* pr = pbuf + (size_t)((((t - 3) & 3) * GROUPS + g) * MPG + rb) * 64;
            pv = load4_nc(pr + lane);
        }
        // fence: ties the loaded regs so MFMA cannot be scheduled before drain
        asm volatile("s_waitcnt vmcnt(0)"
                     : "+v"(a0), "+v"(a1), "+v"(a2), "+v"(a3), "+v"(pv));
        if (wave == 1 && rb < MPG && t >= 3) {
            float v = pv;
            v += __shfl_xor(v, 1); v += __shfl_xor(v, 2); v += __shfl_xor(v, 4);
            v += __shfl_xor(v, 8); v += __shfl_xor(v, 16); v += __shfl_xor(v, 32);
            if (lane == 0) out[(size_t)(g * MPG + rb) * T + (t - 3)] = v + bl;
        }

        // ---- phase B: MFMA. wave w: 8 n-tiles x 16 batches x K/8 ----
        bf16x8 a[4];
        a[0] = __builtin_bit_cast(bf16x8, a0);
        a[1] = __builtin_bit_cast(bf16x8, a1);
        a[2] = __builtin_bit_cast(bf16x8, a2);
        a[3] = __builtin_bit_cast(bf16x8, a3);
        floatx4 acc[8];
        #pragma unroll
        for (int ntl = 0; ntl < 8; ++ntl) acc[ntl] = (floatx4){0.f, 0.f, 0.f, 0.f};
        #pragma unroll
        for (int kt = 0; kt < 4; ++kt) {
            #pragma unroll
            for (int ntl = 0; ntl < 8; ++ntl)
                acc[ntl] = __builtin_amdgcn_mfma_f32_16x16x32_bf16(a[kt], w_hi[ntl][kt], acc[ntl], 0, 0, 0);
        }
        // C/D: col(l15)=dim-in-tile, rows(q*4+r)=batches -> one b128 per ntl
        #pragma unroll
        for (int ntl = 0; ntl < 8; ++ntl)
            *(floatx4*)&Dlds[wave][ntl][l15][q * 4] = acc[ntl];
        __syncthreads();   // post-B: Dlds complete; all-32 polls merged block-wide

        // ---- phase C: b128 kk-sum, gate<->batch transpose, pointwise, publish ----
        {
            // this thread reads gate q's kk-chain for dims pj, batches bq*4..+3
            const float* rbase = &Dlds[0][q * 2 + nhi][l15][bq * 4];
            floatx4 S = *(const floatx4*)rbase;
            #pragma unroll
            for (int kk = 1; kk < 8; ++kk)
                S = S + *(const floatx4*)(rbase + kk * 2560);   // kk stride 8*16*20

            // 4x4 transpose across lane quads: gg[i] = gate i, batch bq*4+q
            float a4[4] = {S[0], S[1], S[2], S[3]};
            float cc[4], gg[4];
            #pragma unroll
            for (int j = 0; j < 4; ++j) {
                float tv = __shfl_xor(a4[j ^ 1], 16);
                cc[j] = ((j ^ q) & 1) ? tv : a4[j];
            }
            #pragma unroll
            for (int j = 0; j < 4; ++j) {
                float tv = __shfl_xor(cc[j ^ 2], 32);
                gg[j] = ((j ^ q) & 2) ? tv : cc[j];
            }

            float gv[4];
            if (t == 0) {
                float s0 = s0_lds[pm];
                #pragma unroll
                for (int gt = 0; gt < 4; ++gt) gv[gt] = gg[gt] + bias0_p[gt] - wih0_p[gt] * s0;
            } else {
                #pragma unroll
                for (int gt = 0; gt < 4; ++gt) gv[gt] = gg[gt] + bias_p[gt];
            }
            float ig  = sigmoidf_(gv[0]);
            float fg  = sigmoidf_(gv[1]);
            float gt_ = tanhf(gv[2]);
            float og  = sigmoidf_(gv[3]);
            cstate = fg * cstate + ig * gt_;
            float hnew = og * tanhf(cstate);

            // h publish: this thread's bf16 into parity (t+1)&1
            store2_wt(((t + 1) & 1) ? (void*)hdst1 : (void*)hdst0,
                      (unsigned int)bf16_rne(hnew));

            // po partial per (batch, dim-half): reduce over 16 dim lanes
            float po = wlin_p * hnew;
            po += __shfl_xor(po, 1); po += __shfl_xor(po, 2);
            po += __shfl_xor(po, 4); po += __shfl_xor(po, 8);
            if (l15 == 0)
                store4_wt(pbuf + (size_t)(((t & 3) * GROUPS + g) * MPG + pm) * 64
                          + nhi * 32 + rb, po);
        }
        // each wave drains ITS OWN stores; 8 concurrent drains, then merge
        asm volatile("s_waitcnt vmcnt(0)" ::: "memory");
        __syncthreads();   // post-C: all h/pbuf stores committed block-wide

        // arrive: fire-and-forget (consumers' polls absorb the commit latency)
        if (tid == 0)
            __hip_atomic_store(&flags[rb], (unsigned int)(t + 2),
                               __ATOMIC_RELAXED, __HIP_MEMORY_SCOPE_AGENT);
    }

    // ---- epilogue: output columns T-3, T-2, T-1 (all-32 poll, once) ----
    if (wave == 1 && rb < MPG) {
        {
            const unsigned int gen = (unsigned int)(T + 1);
            for (;;) {
                unsigned int v = __hip_atomic_load(&flags[lane & 31], __ATOMIC_RELAXED,
                                                   __HIP_MEMORY_SCOPE_AGENT);
                if (__all((int)(v >= gen))) break;
            }
        }
        for (int tt = T - 3; tt < T; ++tt) {
            const float* pr = pbuf + (size_t)(((tt & 3) * GROUPS + g) * MPG + rb) * 64;
            float v = load4_ncw(pr + lane);
            v += __shfl_xor(v, 1); v += __shfl_xor(v, 2); v += __shfl_xor(v, 4);
            v += __shfl_xor(v, 8); v += __shfl_xor(v, 16); v += __shfl_xor(v, 32);
            if (lane == 0) out[(size_t)(g * MPG + rb) * T + tt] = v + bl;
        }
    }
}

extern "C" void kernel_launch(void* const* d_in, const int* in_sizes, int n_in,
                              void* d_out, int out_size, void* d_ws, size_t ws_size,
                              hipStream_t stream) {
    const float* hidden0 = (const float*)d_in[0];
    const float* cell0   = (const float*)d_in[1];
    const float* Wih     = (const float*)d_in[2];
    const float* Whh     = (const float*)d_in[3];
    const float* bih     = (const float*)d_in[4];
    const float* bhh     = (const float*)d_in[5];
    const float* Wlin    = (const float*)d_in[6];
    const float* blin    = (const float*)d_in[7];
    float* out = (float*)d_out;
    float* ws  = (float*)d_ws;

    // zero the barrier flags
    hipMemsetAsync(d_ws, 0, 4096, stream);

    void* args[] = { &hidden0, &cell0, &Wih, &Whh, &bih, &bhh, &Wlin, &blin,
                     &out, &ws };
    hipLaunchCooperativeKernel((const void*)decoder_kernel,
                               dim3(GROUPS * BPG), dim3(NTHR), args, 0, stream);
}

// Round 7
// 1062.679 us; speedup vs baseline: 1.3605x; 1.1176x over previous
//
#include <hip/hip_runtime.h>
#include <math.h>

#define H      1024
#define B      128
#define T      256
#define GROUPS 8        // 8 groups x 32 blocks = 256 blocks (1/CU target)
#define BPG    32       // blocks per group; block owns 32 dims = 128 gate rows
#define NTHR   512
#define MPG    16       // batches per group
#define DPB    32       // dims per block
#define GRP_SHORTS (MPG * H)               // 16384 shorts = 32KB per group per slot
#define GRP_STRIDE (GROUPS * GRP_SHORTS)   // shorts per h-ring slot (all groups)
#define HSLOTS 4
#define POISON 0x7F807F80u                 // bf16 +inf pair: unreachable by h=og*tanh(c)
#define SPIN_MAX 32768                     // ~30ms; converts protocol bug into visible
                                           // wrong-answer instead of a hung container

typedef __attribute__((ext_vector_type(8))) short  bf16x8;
typedef __attribute__((ext_vector_type(4))) float  floatx4;
typedef __attribute__((ext_vector_type(4))) int    int4v;

static __device__ __forceinline__ unsigned short bf16_rne(float f) {
    unsigned int u = __float_as_uint(f);
    u += 0x7FFF + ((u >> 16) & 1);
    return (unsigned short)(u >> 16);
}
static __device__ __forceinline__ float sigmoidf_(float x) { return 1.0f / (1.0f + __expf(-x)); }

// write-through stores: land at the device coherence point, leave no dirty L2
// line behind => no buffer_wbl2 needed anywhere in the loop (R0-proven).
static __device__ __forceinline__ void store16_wt(void* p, int4v v) {
    asm volatile("global_store_dwordx4 %0, %1, off sc0 sc1" :: "v"(p), "v"(v) : "memory");
}
static __device__ __forceinline__ void store4_wt(void* p, float v) {
    asm volatile("global_store_dword %0, %1, off sc0 sc1" :: "v"(p), "v"(v) : "memory");
}
static __device__ __forceinline__ void storeu4_wt(void* p, unsigned int v) {
    asm volatile("global_store_dword %0, %1, off sc0 sc1" :: "v"(p), "v"(v) : "memory");
}
// coherence-point loads (bypass L1+L2): always fresh, no acquire-inv needed.
static __device__ __forceinline__ int4v load16_nc(const void* p) {
    int4v v;   // no internal waitcnt — caller fences
    asm volatile("global_load_dwordx4 %0, %1, off sc0 sc1" : "=v"(v) : "v"(p) : "memory");
    return v;
}
static __device__ __forceinline__ float load4_ncw(const void* p) {
    float v;
    asm volatile("global_load_dword %0, %1, off sc0 sc1\n\ts_waitcnt vmcnt(0)"
                 : "=v"(v) : "v"(p) : "memory");
    return v;
}
// a 16B chunk is valid iff no dword equals the poison pair. Producers write
// dword-paired values (single dword stores = atomic), so a dword is either
// full-poison or full-data — never torn.
static __device__ __forceinline__ int clean4(int4v c) {
    return (c[0] != (int)POISON) & (c[1] != (int)POISON) &
           (c[2] != (int)POISON) & (c[3] != (int)POISON);
}

// Persistent LSTM decoder. 8 groups x 32 blocks (static grouping). Group g owns
// batches [16g,16g+16); block rb owns dims [32rb,32rb+32) => 128 gate rows
// (8 n-tiles). W' = W_hh + W_ih[:,0](x)W_lin, hi-bf16, in registers. Wave w
// owns K-eighth [128w,128w+128) and ALL 8 n-tiles.
//
// R7 == R6 (flagless data-polling) + bounded spins (SPIN_MAX):
// h lives in a DEPTH-4 ring (slot t&3 holds h_t); publishes are fire-and-
// forget paired-dword WT stores; consumers poll the data directly for the
// absence of the poison sentinel (bf16 +inf pair — unreachable, |h|<=1).
// Each block re-poisons its OWN 1KB chunk of slot (t+3)&3 each step.
// Safety certificates (drain point = the vmcnt(0) inside the poll loop):
//  - I poison slot (t-1)&3 at step t C only after my post-B of step t, which
//    merged all 8 waves' observations of h_t => all 32 peers passed their
//    step t-1 phase A (their reads of slot (t-1)&3 are complete).
//  - My poison (step t C) drains at my step t+1 phase A vmcnt(0), strictly
//    before I publish h_{t+2} into that slot at step t+2 C (program order).
//  - Stale-accept impossible: consumer polls slot (t+1)&3 for h_{t+1} only
//    after observing h_t (step t A); h_t was published after its producer's
//    step t-1 phase A drain, which committed the poison of slot (t+1)&3
//    (issued step t-2 C). Two-fence margin at depth 4.
// Flags survive only in the preamble (order poisons before h0) and epilogue.
__global__ __launch_bounds__(NTHR, 2) void decoder_kernel(
    const float* __restrict__ hidden0, const float* __restrict__ cell0,
    const float* __restrict__ Wih,     const float* __restrict__ Whh,
    const float* __restrict__ bih,     const float* __restrict__ bhh,
    const float* __restrict__ Wlin,    const float* __restrict__ blin,
    float* __restrict__ out,           float* __restrict__ ws)
{
    __shared__ __align__(16) float Dlds[8][8][16][20];   // 80 KB: [kk][ntl][n][m+pad4]
    __shared__ float s0_lds[MPG];

    const int blk  = blockIdx.x;
    const int g    = blk >> 5;          // group 0..7
    const int rb   = blk & 31;          // block in group 0..31
    const int tid  = threadIdx.x;
    const int lane = tid & 63;
    const int wave = tid >> 6;          // 8 waves: wave = K-eighth
    const int l15  = lane & 15;
    const int q    = lane >> 4;

    // ws: flags 8 groups x 64 uints | h ring 1MB (4 slots) | pbuf ring 128 KB
    unsigned int*   flags = (unsigned int*)ws + g * 64;            // 32 used
    unsigned short* hbuf  = (unsigned short*)((char*)ws + 4096);   // [4][G][GRP_SHORTS]
    float*          pbuf  = (float*)((char*)ws + 4096
                             + (size_t)HSLOTS * GRP_STRIDE * 2);   // [4][G][MPG][64]

    // ---- W' hi-bf16 B-fragments in registers: 8 n-tiles x K/8 = 32 frags ----
    bf16x8 w_hi[8][4];
    #pragma unroll
    for (int ntl = 0; ntl < 8; ++ntl) {
        const int gate = ntl >> 1;
        const int row  = gate * H + rb * DPB + (ntl & 1) * 16 + l15;
        const float* wrow  = Whh + (size_t)row * H;
        const float  wih0r = Wih[row * 2];
        #pragma unroll
        for (int kt = 0; kt < 4; ++kt) {
            const int k0 = wave * 128 + kt * 32 + q * 8;
            #pragma unroll
            for (int j = 0; j < 8; ++j) {
                float w = wrow[k0 + j] + wih0r * Wlin[k0 + j];
                w_hi[ntl][kt][j] = (short)bf16_rne(w);
            }
        }
    }

    // ---- pointwise-thread constants (R5 mapping): pm=bq*4+q, pj=nhi*16+l15 ----
    const int bq    = wave >> 1;              // batch quad 0..3
    const int nhi   = wave & 1;               // dim half 0..1
    const int pm    = bq * 4 + q;             // batch in group 0..15
    const int pj    = nhi * 16 + l15;         // dim within block 0..31
    const int bglob = g * MPG + pm;
    const int kdim  = rb * DPB + pj;
    const float bl  = blin[0];
    float bias_p[4], bias0_p[4], wih0_p[4];
    #pragma unroll
    for (int gt = 0; gt < 4; ++gt) {
        int r2 = gt * H + kdim;
        float b0 = bih[r2] + bhh[r2];
        float w0 = Wih[r2 * 2];
        bias0_p[gt] = b0;
        wih0_p[gt]  = w0;
        bias_p[gt]  = b0 + Wih[r2 * 2 + 1] + w0 * bl;   // folded bias (t>=1)
    }
    float cstate = cell0[(size_t)bglob * H + kdim];
    const float wlin_p = Wlin[kdim];

    // h addressing: chunk layout short index within a (slot,group) region
    const size_t hoff = (size_t)rb * 512 + (pj >> 3) * 128 + pm * 8 + (pj & 7);
    unsigned short* hgrp   = hbuf + (size_t)g * GRP_SHORTS;    // slot 0 of my group
    unsigned short* hpairb = hgrp + hoff;                      // my pair addr (even lanes)
    unsigned short* mychk  = hgrp + (size_t)rb * 512;          // my 1KB chunk, slot 0

    const int4v pois = { (int)POISON, (int)POISON, (int)POISON, (int)POISON };

    // ---- preamble: poison own chunk in ALL 4 slots (before any h0 publish) ----
    if (lane < 8) {
        #pragma unroll
        for (int s = 0; s < HSLOTS; ++s)
            store16_wt((char*)(mychk + (size_t)s * GRP_STRIDE) + wave * 128 + lane * 16,
                       pois);
    }

    // ---- s0[m] = Wlin . h0[m]  (t=0 rank-1 correction; old thread mapping) ----
    {
        const int pm_o = tid >> 5, pj_o = tid & 31;
        const float* hp = hidden0 + (size_t)(g * MPG + pm_o) * H + pj_o * 32;
        const float* wp = Wlin + pj_o * 32;
        float s = 0.f;
        #pragma unroll 4
        for (int kk = 0; kk < 32; kk += 4) {
            float4 hv = *(const float4*)(hp + kk);
            float4 wv = *(const float4*)(wp + kk);
            s += hv.x * wv.x + hv.y * wv.y + hv.z * wv.z + hv.w * wv.w;
        }
        s += __shfl_xor(s, 1); s += __shfl_xor(s, 2);
        s += __shfl_xor(s, 4); s += __shfl_xor(s, 8); s += __shfl_xor(s, 16);
        if (pj_o == 0) s0_lds[pm_o] = s;
    }

    // one-time flag round: all poisons committed before ANY h0 store issues
    asm volatile("s_waitcnt vmcnt(0)" ::: "memory");
    __syncthreads();
    if (tid == 0)
        __hip_atomic_store(&flags[rb], 1u, __ATOMIC_RELAXED, __HIP_MEMORY_SCOPE_AGENT);
    if (wave == 0) {
        for (int spin = 0; spin < SPIN_MAX; ++spin) {
            unsigned int v = __hip_atomic_load(&flags[lane & 31], __ATOMIC_RELAXED,
                                               __HIP_MEMORY_SCOPE_AGENT);
            if (__all((int)(v >= 1u))) break;
        }
    }
    __syncthreads();

    // ---- h0 publish into slot 0: paired-dword, fire-and-forget ----
    {
        float v0 = hidden0[(size_t)bglob * H + kdim];
        unsigned int hs = bf16_rne(v0);
        unsigned int pw = (unsigned int)__shfl_xor((int)hs, 1);
        if (!(lane & 1))
            storeu4_wt(hpairb, (hs & 0xFFFFu) | (pw << 16));
    }

    for (int t = 0; t < T; ++t) {
        // ---- phase A: DATA-POLL this wave's 4 chunks of slot t&3 ----
        const char* hsrc = (const char*)(hgrp + (size_t)(t & 3) * GRP_STRIDE)
                         + wave * 4096 + lane * 16;
        int4v a0, a1, a2, a3;
        for (int spin = 0; spin < SPIN_MAX; ++spin) {
            a0 = load16_nc(hsrc);
            a1 = load16_nc(hsrc + 1024);
            a2 = load16_nc(hsrc + 2048);
            a3 = load16_nc(hsrc + 3072);
            // drain point: also commits all of MY prior stores (poison/h/pbuf)
            asm volatile("s_waitcnt vmcnt(0)"
                         : "+v"(a0), "+v"(a1), "+v"(a2), "+v"(a3));
            if (__all(clean4(a0) & clean4(a1) & clean4(a2) & clean4(a3))) break;
        }
        if (wave == 1 && rb < MPG && t >= 3) {
            // batch m = rb: step t-3's 64 partials. Certificate: post-B of t-1
            // observed peers' h_{t-1}, published after the fence that drained
            // their step t-3 pbuf stores.
            const float* pr = pbuf + (size_t)((((t - 3) & 3) * GROUPS + g) * MPG + rb) * 64;
            float v = load4_ncw(pr + lane);
            v += __shfl_xor(v, 1); v += __shfl_xor(v, 2); v += __shfl_xor(v, 4);
            v += __shfl_xor(v, 8); v += __shfl_xor(v, 16); v += __shfl_xor(v, 32);
            if (lane == 0) out[(size_t)(g * MPG + rb) * T + (t - 3)] = v + bl;
        }

        // ---- phase B: MFMA. wave w: 8 n-tiles x 16 batches x K/8 ----
        bf16x8 a[4];
        a[0] = __builtin_bit_cast(bf16x8, a0);
        a[1] = __builtin_bit_cast(bf16x8, a1);
        a[2] = __builtin_bit_cast(bf16x8, a2);
        a[3] = __builtin_bit_cast(bf16x8, a3);
        floatx4 acc[8];
        #pragma unroll
        for (int ntl = 0; ntl < 8; ++ntl) acc[ntl] = (floatx4){0.f, 0.f, 0.f, 0.f};
        #pragma unroll
        for (int kt = 0; kt < 4; ++kt) {
            #pragma unroll
            for (int ntl = 0; ntl < 8; ++ntl)
                acc[ntl] = __builtin_amdgcn_mfma_f32_16x16x32_bf16(a[kt], w_hi[ntl][kt], acc[ntl], 0, 0, 0);
        }
        #pragma unroll
        for (int ntl = 0; ntl < 8; ++ntl)
            *(floatx4*)&Dlds[wave][ntl][l15][q * 4] = acc[ntl];
        __syncthreads();   // post-B: Dlds complete; all-32 data-polls merged

        // ---- phase C ----
        // re-arm: poison my chunk of slot (t+3)&3 == (t-1)&3 (peers' reads of
        // it are certified complete by the merged post-B observations of h_t).
        if (lane < 8)
            store16_wt((char*)(mychk + (size_t)((t + 3) & 3) * GRP_STRIDE)
                       + wave * 128 + lane * 16, pois);
        {
            // b128 kk-sum: gate q's chain for dims pj, batches bq*4..+3
            const float* rbase = &Dlds[0][q * 2 + nhi][l15][bq * 4];
            floatx4 S = *(const floatx4*)rbase;
            #pragma unroll
            for (int kk = 1; kk < 8; ++kk)
                S = S + *(const floatx4*)(rbase + kk * 2560);   // kk stride 8*16*20

            // 4x4 transpose across lane quads: gg[i] = gate i, batch bq*4+q
            float a4[4] = {S[0], S[1], S[2], S[3]};
            float cc[4], gg[4];
            #pragma unroll
            for (int j = 0; j < 4; ++j) {
                float tv = __shfl_xor(a4[j ^ 1], 16);
                cc[j] = ((j ^ q) & 1) ? tv : a4[j];
            }
            #pragma unroll
            for (int j = 0; j < 4; ++j) {
                float tv = __shfl_xor(cc[j ^ 2], 32);
                gg[j] = ((j ^ q) & 2) ? tv : cc[j];
            }

            float gv[4];
            if (t == 0) {
                float s0 = s0_lds[pm];
                #pragma unroll
                for (int gt = 0; gt < 4; ++gt) gv[gt] = gg[gt] + bias0_p[gt] - wih0_p[gt] * s0;
            } else {
                #pragma unroll
                for (int gt = 0; gt < 4; ++gt) gv[gt] = gg[gt] + bias_p[gt];
            }
            float ig  = sigmoidf_(gv[0]);
            float fg  = sigmoidf_(gv[1]);
            float gt_ = tanhf(gv[2]);
            float og  = sigmoidf_(gv[3]);
            cstate = fg * cstate + ig * gt_;
            float hnew = og * tanhf(cstate);

            // h publish into slot (t+1)&3: paired-dword (atomic, never torn),
            // fire-and-forget — consumers' data-polls detect arrival directly
            unsigned int hs = bf16_rne(hnew);
            unsigned int pw = (unsigned int)__shfl_xor((int)hs, 1);
            if (!(lane & 1))
                storeu4_wt(hpairb + (size_t)((t + 1) & 3) * GRP_STRIDE,
                           (hs & 0xFFFFu) | (pw << 16));

            // po partial per (batch, dim-half): reduce over 16 dim lanes
            float po = wlin_p * hnew;
            po += __shfl_xor(po, 1); po += __shfl_xor(po, 2);
            po += __shfl_xor(po, 4); po += __shfl_xor(po, 8);
            if (l15 == 0)
                store4_wt(pbuf + (size_t)(((t & 3) * GROUPS + g) * MPG + pm) * 64
                          + nhi * 32 + rb, po);
        }
        __syncthreads();   // post-C: Dlds safe to overwrite next step
        // no drain, no flag — waves flow straight into step t+1's data-poll
    }

    // ---- epilogue: one flag round orders final pbuf commits, then T-3..T-1 ----
    asm volatile("s_waitcnt vmcnt(0)" ::: "memory");
    __syncthreads();
    if (tid == 0)
        __hip_atomic_store(&flags[rb], 2u, __ATOMIC_RELAXED, __HIP_MEMORY_SCOPE_AGENT);
    if (wave == 1 && rb < MPG) {
        for (int spin = 0; spin < SPIN_MAX; ++spin) {
            unsigned int v = __hip_atomic_load(&flags[lane & 31], __ATOMIC_RELAXED,
                                               __HIP_MEMORY_SCOPE_AGENT);
            if (__all((int)(v >= 2u))) break;
        }
        for (int tt = T - 3; tt < T; ++tt) {
            const float* pr = pbuf + (size_t)(((tt & 3) * GROUPS + g) * MPG + rb) * 64;
            float v = load4_ncw(pr + lane);
            v += __shfl_xor(v, 1); v += __shfl_xor(v, 2); v += __shfl_xor(v, 4);
            v += __shfl_xor(v, 8); v += __shfl_xor(v, 16); v += __shfl_xor(v, 32);
            if (lane == 0) out[(size_t)(g * MPG + rb) * T + tt] = v + bl;
        }
    }
}

extern "C" void kernel_launch(void* const* d_in, const int* in_sizes, int n_in,
                              void* d_out, int out_size, void* d_ws, size_t ws_size,
                              hipStream_t stream) {
    const float* hidden0 = (const float*)d_in[0];
    const float* cell0   = (const float*)d_in[1];
    const float* Wih     = (const float*)d_in[2];
    const float* Whh     = (const float*)d_in[3];
    const float* bih     = (const float*)d_in[4];
    const float* bhh     = (const float*)d_in[5];
    const float* Wlin    = (const float*)d_in[6];
    const float* blin    = (const float*)d_in[7];
    float* out = (float*)d_out;
    float* ws  = (float*)d_ws;

    // zero the preamble/epilogue flags
    hipMemsetAsync(d_ws, 0, 4096, stream);

    void* args[] = { &hidden0, &cell0, &Wih, &Whh, &bih, &bhh, &Wlin, &blin,
                     &out, &ws };
    hipLaunchCooperativeKernel((const void*)decoder_kernel,
                               dim3(GROUPS * BPG), dim3(NTHR), args, 0, stream);
}

// Round 9
// 979.965 us; speedup vs baseline: 1.4754x; 1.0844x over previous
//
#include <hip/hip_runtime.h>
#include <math.h>

#define H      1024
#define B      128
#define T      256
#define GROUPS 8        // 8 groups x 32 blocks = 256 blocks (1/CU target)
#define BPG    32       // blocks per group; block owns 32 dims = 128 gate rows
#define NTHR   512
#define MPG    16       // batches per group
#define DPB    32       // dims per block
#define GRP_SHORTS (MPG * H)               // 16384 shorts = 32KB per group per slot
#define GRP_STRIDE (GROUPS * GRP_SHORTS)   // shorts per h-ring slot (all groups)
#define HSLOTS 4
#define POISON 0x7F807F80u                 // bf16 +inf pair: unreachable by h=og*tanh(c)
#define SPIN_MAX 32768                     // ~30ms; converts protocol bug into visible
                                           // wrong-answer instead of a hung container

typedef __attribute__((ext_vector_type(8))) short  bf16x8;
typedef __attribute__((ext_vector_type(4))) float  floatx4;
typedef __attribute__((ext_vector_type(4))) int    int4v;

static __device__ __forceinline__ unsigned short bf16_rne(float f) {
    unsigned int u = __float_as_uint(f);
    u += 0x7FFF + ((u >> 16) & 1);
    return (unsigned short)(u >> 16);
}
static __device__ __forceinline__ float sigmoidf_(float x) { return 1.0f / (1.0f + __expf(-x)); }

// write-through stores: land at the device coherence point, leave no dirty L2
// line behind => no buffer_wbl2 needed anywhere in the loop (R0-proven).
static __device__ __forceinline__ void store16_wt(void* p, int4v v) {
    asm volatile("global_store_dwordx4 %0, %1, off sc0 sc1" :: "v"(p), "v"(v) : "memory");
}
static __device__ __forceinline__ void store4_wt(void* p, float v) {
    asm volatile("global_store_dword %0, %1, off sc0 sc1" :: "v"(p), "v"(v) : "memory");
}
static __device__ __forceinline__ void storeu4_wt(void* p, unsigned int v) {
    asm volatile("global_store_dword %0, %1, off sc0 sc1" :: "v"(p), "v"(v) : "memory");
}
// coherence-point loads (bypass L1+L2): always fresh, no acquire-inv needed.
static __device__ __forceinline__ int4v load16_nc(const void* p) {
    int4v v;   // no internal waitcnt — caller fences
    asm volatile("global_load_dwordx4 %0, %1, off sc0 sc1" : "=v"(v) : "v"(p) : "memory");
    return v;
}
static __device__ __forceinline__ float load4_nc(const void* p) {
    float v;   // no internal waitcnt — drained by the next poll fence
    asm volatile("global_load_dword %0, %1, off sc0 sc1" : "=v"(v) : "v"(p) : "memory");
    return v;
}
static __device__ __forceinline__ float load4_ncw(const void* p) {
    float v;
    asm volatile("global_load_dword %0, %1, off sc0 sc1\n\ts_waitcnt vmcnt(0)"
                 : "=v"(v) : "v"(p) : "memory");
    return v;
}
// a 16B chunk is valid iff no dword equals the poison pair. Producers write
// dword-paired values (single dword stores = atomic), so a dword is either
// full-poison or full-data — never torn.
static __device__ __forceinline__ int clean4(int4v c) {
    return (c[0] != (int)POISON) & (c[1] != (int)POISON) &
           (c[2] != (int)POISON) & (c[3] != (int)POISON);
}

// Persistent LSTM decoder. 8 groups x 32 blocks (static grouping). Group g owns
// batches [16g,16g+16); block rb owns dims [32rb,32rb+32) => 128 gate rows
// (8 n-tiles). W' = W_hh + W_ih[:,0](x)W_lin, hi-bf16, in registers. Wave w
// owns K-eighth [128w,128w+128) and ALL 8 n-tiles.
//
// R9 == R7 (proven: flagless data-polling, depth-4 h ring, poison sentinel,
// polls issued INSIDE phase A after the post-C barrier) + ONE change:
//  - PRE-ISSUED PBUF READ (wave1): the partial-sum load consumed at step t is
//    issued at the end of phase C of step t-1 (load4_nc, no waitcnt) and
//    drained by the poll loop's register-tied vmcnt(0). Certificate: my
//    pre-issue follows my post-B of step t-1 (all-32 observations of h_{t-1}
//    merged); each peer's step t-3 pbuf store committed before its h_{t-2}
//    publish (its phase-A drain sits between), hence before any h_{t-1}
//    observation. Clobber of slot (t-3)&3 happens at peers' step t+1 phase C,
//    causally after my h_{t+1} publish, which follows my step t phase A where
//    pv drained. One full phase of margin on both sides.
// R8's other deltas (pre-issued h polls, publish-first reorder) are REVERTED
// pending isolated testing — R8 failed with all three bundled.
__global__ __launch_bounds__(NTHR, 2) void decoder_kernel(
    const float* __restrict__ hidden0, const float* __restrict__ cell0,
    const float* __restrict__ Wih,     const float* __restrict__ Whh,
    const float* __restrict__ bih,     const float* __restrict__ bhh,
    const float* __restrict__ Wlin,    const float* __restrict__ blin,
    float* __restrict__ out,           float* __restrict__ ws)
{
    __shared__ __align__(16) float Dlds[8][8][16][20];   // 80 KB: [kk][ntl][n][m+pad4]
    __shared__ float s0_lds[MPG];

    const int blk  = blockIdx.x;
    const int g    = blk >> 5;          // group 0..7
    const int rb   = blk & 31;          // block in group 0..31
    const int tid  = threadIdx.x;
    const int lane = tid & 63;
    const int wave = tid >> 6;          // 8 waves: wave = K-eighth
    const int l15  = lane & 15;
    const int q    = lane >> 4;

    // ws: flags 8 groups x 64 uints | h ring 1MB (4 slots) | pbuf ring 128 KB
    unsigned int*   flags = (unsigned int*)ws + g * 64;            // 32 used
    unsigned short* hbuf  = (unsigned short*)((char*)ws + 4096);   // [4][G][GRP_SHORTS]
    float*          pbuf  = (float*)((char*)ws + 4096
                             + (size_t)HSLOTS * GRP_STRIDE * 2);   // [4][G][MPG][64]

    // ---- W' hi-bf16 B-fragments in registers: 8 n-tiles x K/8 = 32 frags ----
    bf16x8 w_hi[8][4];
    #pragma unroll
    for (int ntl = 0; ntl < 8; ++ntl) {
        const int gate = ntl >> 1;
        const int row  = gate * H + rb * DPB + (ntl & 1) * 16 + l15;
        const float* wrow  = Whh + (size_t)row * H;
        const float  wih0r = Wih[row * 2];
        #pragma unroll
        for (int kt = 0; kt < 4; ++kt) {
            const int k0 = wave * 128 + kt * 32 + q * 8;
            #pragma unroll
            for (int j = 0; j < 8; ++j) {
                float w = wrow[k0 + j] + wih0r * Wlin[k0 + j];
                w_hi[ntl][kt][j] = (short)bf16_rne(w);
            }
        }
    }

    // ---- pointwise-thread constants (R5 mapping): pm=bq*4+q, pj=nhi*16+l15 ----
    const int bq    = wave >> 1;              // batch quad 0..3
    const int nhi   = wave & 1;               // dim half 0..1
    const int pm    = bq * 4 + q;             // batch in group 0..15
    const int pj    = nhi * 16 + l15;         // dim within block 0..31
    const int bglob = g * MPG + pm;
    const int kdim  = rb * DPB + pj;
    const float bl  = blin[0];
    float bias_p[4], bias0_p[4], wih0_p[4];
    #pragma unroll
    for (int gt = 0; gt < 4; ++gt) {
        int r2 = gt * H + kdim;
        float b0 = bih[r2] + bhh[r2];
        float w0 = Wih[r2 * 2];
        bias0_p[gt] = b0;
        wih0_p[gt]  = w0;
        bias_p[gt]  = b0 + Wih[r2 * 2 + 1] + w0 * bl;   // folded bias (t>=1)
    }
    float cstate = cell0[(size_t)bglob * H + kdim];
    const float wlin_p = Wlin[kdim];

    // h addressing: chunk layout short index within a (slot,group) region
    const size_t hoff = (size_t)rb * 512 + (pj >> 3) * 128 + pm * 8 + (pj & 7);
    unsigned short* hgrp   = hbuf + (size_t)g * GRP_SHORTS;    // slot 0 of my group
    unsigned short* hpairb = hgrp + hoff;                      // my pair addr (even lanes)
    unsigned short* mychk  = hgrp + (size_t)rb * 512;          // my 1KB chunk, slot 0

    const int4v pois = { (int)POISON, (int)POISON, (int)POISON, (int)POISON };

    // ---- preamble: poison own chunk in ALL 4 slots (before any h0 publish) ----
    if (lane < 8) {
        #pragma unroll
        for (int s = 0; s < HSLOTS; ++s)
            store16_wt((char*)(mychk + (size_t)s * GRP_STRIDE) + wave * 128 + lane * 16,
                       pois);
    }

    // ---- s0[m] = Wlin . h0[m]  (t=0 rank-1 correction; old thread mapping) ----
    {
        const int pm_o = tid >> 5, pj_o = tid & 31;
        const float* hp = hidden0 + (size_t)(g * MPG + pm_o) * H + pj_o * 32;
        const float* wp = Wlin + pj_o * 32;
        float s = 0.f;
        #pragma unroll 4
        for (int kk = 0; kk < 32; kk += 4) {
            float4 hv = *(const float4*)(hp + kk);
            float4 wv = *(const float4*)(wp + kk);
            s += hv.x * wv.x + hv.y * wv.y + hv.z * wv.z + hv.w * wv.w;
        }
        s += __shfl_xor(s, 1); s += __shfl_xor(s, 2);
        s += __shfl_xor(s, 4); s += __shfl_xor(s, 8); s += __shfl_xor(s, 16);
        if (pj_o == 0) s0_lds[pm_o] = s;
    }

    // one-time flag round: all poisons committed before ANY h0 store issues
    asm volatile("s_waitcnt vmcnt(0)" ::: "memory");
    __syncthreads();
    if (tid == 0)
        __hip_atomic_store(&flags[rb], 1u, __ATOMIC_RELAXED, __HIP_MEMORY_SCOPE_AGENT);
    if (wave == 0) {
        for (int spin = 0; spin < SPIN_MAX; ++spin) {
            unsigned int v = __hip_atomic_load(&flags[lane & 31], __ATOMIC_RELAXED,
                                               __HIP_MEMORY_SCOPE_AGENT);
            if (__all((int)(v >= 1u))) break;
        }
    }
    __syncthreads();

    // ---- h0 publish into slot 0: paired-dword, fire-and-forget ----
    {
        float v0 = hidden0[(size_t)bglob * H + kdim];
        unsigned int hs = bf16_rne(v0);
        unsigned int pw = (unsigned int)__shfl_xor((int)hs, 1);
        if (!(lane & 1))
            storeu4_wt(hpairb, (hs & 0xFFFFu) | (pw << 16));
    }

    float pv = 0.f;   // pre-issued pbuf partial (wave1), drained by poll fence

    for (int t = 0; t < T; ++t) {
        // ---- phase A: DATA-POLL this wave's 4 chunks of slot t&3 ----
        const char* hsrc = (const char*)(hgrp + (size_t)(t & 3) * GRP_STRIDE)
                         + wave * 4096 + lane * 16;
        int4v a0, a1, a2, a3;
        for (int spin = 0; spin < SPIN_MAX; ++spin) {
            a0 = load16_nc(hsrc);
            a1 = load16_nc(hsrc + 1024);
            a2 = load16_nc(hsrc + 2048);
            a3 = load16_nc(hsrc + 3072);
            // drain point: commits all of MY prior stores (poison/h/pbuf) and
            // completes these loads + the pre-issued pv load
            asm volatile("s_waitcnt vmcnt(0)"
                         : "+v"(a0), "+v"(a1), "+v"(a2), "+v"(a3), "+v"(pv));
            if (__all(clean4(a0) & clean4(a1) & clean4(a2) & clean4(a3))) break;
        }
        if (wave == 1 && rb < MPG && t >= 3) {
            // batch m = rb: step t-3's 64 partials (pre-issued last phase C)
            float v = pv;
            v += __shfl_xor(v, 1); v += __shfl_xor(v, 2); v += __shfl_xor(v, 4);
            v += __shfl_xor(v, 8); v += __shfl_xor(v, 16); v += __shfl_xor(v, 32);
            if (lane == 0) out[(size_t)(g * MPG + rb) * T + (t - 3)] = v + bl;
        }

        // ---- phase B: MFMA. wave w: 8 n-tiles x 16 batches x K/8 ----
        bf16x8 a[4];
        a[0] = __builtin_bit_cast(bf16x8, a0);
        a[1] = __builtin_bit_cast(bf16x8, a1);
        a[2] = __builtin_bit_cast(bf16x8, a2);
        a[3] = __builtin_bit_cast(bf16x8, a3);
        floatx4 acc[8];
        #pragma unroll
        for (int ntl = 0; ntl < 8; ++ntl) acc[ntl] = (floatx4){0.f, 0.f, 0.f, 0.f};
        #pragma unroll
        for (int kt = 0; kt < 4; ++kt) {
            #pragma unroll
            for (int ntl = 0; ntl < 8; ++ntl)
                acc[ntl] = __builtin_amdgcn_mfma_f32_16x16x32_bf16(a[kt], w_hi[ntl][kt], acc[ntl], 0, 0, 0);
        }
        #pragma unroll
        for (int ntl = 0; ntl < 8; ++ntl)
            *(floatx4*)&Dlds[wave][ntl][l15][q * 4] = acc[ntl];
        __syncthreads();   // post-B: Dlds complete; all-32 data-polls merged

        // ---- phase C (R7 order: poison first, compute, publish, pbuf) ----
        // re-arm: poison my chunk of slot (t+3)&3 == (t-1)&3 (peers' reads of
        // it are certified complete by the merged post-B observations of h_t)
        if (lane < 8)
            store16_wt((char*)(mychk + (size_t)((t + 3) & 3) * GRP_STRIDE)
                       + wave * 128 + lane * 16, pois);
        {
            // b128 kk-sum: gate q's chain for dims pj, batches bq*4..+3
            const float* rbase = &Dlds[0][q * 2 + nhi][l15][bq * 4];
            floatx4 S = *(const floatx4*)rbase;
            #pragma unroll
            for (int kk = 1; kk < 8; ++kk)
                S = S + *(const floatx4*)(rbase + kk * 2560);   // kk stride 8*16*20

            // 4x4 transpose across lane quads: gg[i] = gate i, batch bq*4+q
            float a4[4] = {S[0], S[1], S[2], S[3]};
            float cc[4], gg[4];
            #pragma unroll
            for (int j = 0; j < 4; ++j) {
                float tv = __shfl_xor(a4[j ^ 1], 16);
                cc[j] = ((j ^ q) & 1) ? tv : a4[j];
            }
            #pragma unroll
            for (int j = 0; j < 4; ++j) {
                float tv = __shfl_xor(cc[j ^ 2], 32);
                gg[j] = ((j ^ q) & 2) ? tv : cc[j];
            }

            float gv[4];
            if (t == 0) {
                float s0 = s0_lds[pm];
                #pragma unroll
                for (int gt = 0; gt < 4; ++gt) gv[gt] = gg[gt] + bias0_p[gt] - wih0_p[gt] * s0;
            } else {
                #pragma unroll
                for (int gt = 0; gt < 4; ++gt) gv[gt] = gg[gt] + bias_p[gt];
            }
            float ig  = sigmoidf_(gv[0]);
            float fg  = sigmoidf_(gv[1]);
            float gt_ = tanhf(gv[2]);
            float og  = sigmoidf_(gv[3]);
            cstate = fg * cstate + ig * gt_;
            float hnew = og * tanhf(cstate);

            // h publish into slot (t+1)&3: paired-dword (atomic, never torn),
            // fire-and-forget — consumers' data-polls detect arrival directly
            unsigned int hs = bf16_rne(hnew);
            unsigned int pw = (unsigned int)__shfl_xor((int)hs, 1);
            if (!(lane & 1))
                storeu4_wt(hpairb + (size_t)((t + 1) & 3) * GRP_STRIDE,
                           (hs & 0xFFFFu) | (pw << 16));

            // po partial per (batch, dim-half): reduce over 16 dim lanes
            float po = wlin_p * hnew;
            po += __shfl_xor(po, 1); po += __shfl_xor(po, 2);
            po += __shfl_xor(po, 4); po += __shfl_xor(po, 8);
            if (l15 == 0)
                store4_wt(pbuf + (size_t)(((t & 3) * GROUPS + g) * MPG + pm) * 64
                          + nhi * 32 + rb, po);
        }

        // ---- NEW: pre-issue step t+1's pbuf read (wave1; slot (t-2)&3,
        //      certified committed by this step's post-B all-32 merge) ----
        if (wave == 1 && rb < MPG && t >= 2 && t < T - 1) {
            const float* pr = pbuf + (size_t)((((t - 2) & 3) * GROUPS + g) * MPG + rb) * 64;
            pv = load4_nc(pr + lane);
        }
        __syncthreads();   // post-C: Dlds safe to overwrite next step
        // no drain, no flag — waves flow straight into step t+1's data-poll
    }

    // ---- epilogue: one flag round orders final pbuf commits, then T-3..T-1 ----
    asm volatile("s_waitcnt vmcnt(0)" ::: "memory");
    __syncthreads();
    if (tid == 0)
        __hip_atomic_store(&flags[rb], 2u, __ATOMIC_RELAXED, __HIP_MEMORY_SCOPE_AGENT);
    if (wave == 1 && rb < MPG) {
        for (int spin = 0; spin < SPIN_MAX; ++spin) {
            unsigned int v = __hip_atomic_load(&flags[lane & 31], __ATOMIC_RELAXED,
                                               __HIP_MEMORY_SCOPE_AGENT);
            if (__all((int)(v >= 2u))) break;
        }
        for (int tt = T - 3; tt < T; ++tt) {
            const float* pr = pbuf + (size_t)(((tt & 3) * GROUPS + g) * MPG + rb) * 64;
            float v = load4_ncw(pr + lane);
            v += __shfl_xor(v, 1); v += __shfl_xor(v, 2); v += __shfl_xor(v, 4);
            v += __shfl_xor(v, 8); v += __shfl_xor(v, 16); v += __shfl_xor(v, 32);
            if (lane == 0) out[(size_t)(g * MPG + rb) * T + tt] = v + bl;
        }
    }
}

extern "C" void kernel_launch(void* const* d_in, const int* in_sizes, int n_in,
                              void* d_out, int out_size, void* d_ws, size_t ws_size,
                              hipStream_t stream) {
    const float* hidden0 = (const float*)d_in[0];
    const float* cell0   = (const float*)d_in[1];
    const float* Wih     = (const float*)d_in[2];
    const float* Whh     = (const float*)d_in[3];
    const float* bih     = (const float*)d_in[4];
    const float* bhh     = (const float*)d_in[5];
    const float* Wlin    = (const float*)d_in[6];
    const float* blin    = (const float*)d_in[7];
    float* out = (float*)d_out;
    float* ws  = (float*)d_ws;

    // zero the preamble/epilogue flags
    hipMemsetAsync(d_ws, 0, 4096, stream);

    void* args[] = { &hidden0, &cell0, &Wih, &Whh, &bih, &bhh, &Wlin, &blin,
                     &out, &ws };
    hipLaunchCooperativeKernel((const void*)decoder_kernel,
                               dim3(GROUPS * BPG), dim3(NTHR), args, 0, stream);
}

// Round 11
// 938.573 us; speedup vs baseline: 1.5404x; 1.0441x over previous
//
#include <hip/hip_runtime.h>
#include <math.h>

#define H      1024
#define B      128
#define T      256
#define GROUPS 8        // 8 groups x 32 blocks = 256 blocks (1/CU target)
#define BPG    32       // blocks per group; block owns 32 dims = 128 gate rows
#define NTHR   512
#define MPG    16       // batches per group
#define DPB    32       // dims per block
#define GRP_SHORTS (MPG * H)               // 16384 shorts = 32KB per group per slot
#define GRP_STRIDE (GROUPS * GRP_SHORTS)   // shorts per h-ring slot (all groups)
#define HSLOTS 4
#define POISON 0x7F807F80u                 // bf16 +inf pair: unreachable by h=og*tanh(c)
#define SPIN_MAX 32768                     // ~30ms; converts protocol bug into visible
                                           // wrong-answer instead of a hung container

typedef __attribute__((ext_vector_type(8))) short  bf16x8;
typedef __attribute__((ext_vector_type(4))) float  floatx4;
typedef __attribute__((ext_vector_type(4))) int    int4v;

static __device__ __forceinline__ unsigned short bf16_rne(float f) {
    unsigned int u = __float_as_uint(f);
    u += 0x7FFF + ((u >> 16) & 1);
    return (unsigned short)(u >> 16);
}
static __device__ __forceinline__ float sigmoidf_(float x) { return 1.0f / (1.0f + __expf(-x)); }
// fast tanh: exact +/-1 saturation (exp overflow -> inf -> 2/inf = 0), no NaN
// for finite x; |err| ~1e-7 << bf16 rounding. Replaces branchy libm tanhf on
// the Dlds->publish critical path (2 serial uses per step).
static __device__ __forceinline__ float tanhf_fast(float x) {
    return 1.0f - 2.0f / (__expf(2.0f * x) + 1.0f);
}

// write-through stores: land at the device coherence point, leave no dirty L2
// line behind => no buffer_wbl2 needed anywhere in the loop (R0-proven).
static __device__ __forceinline__ void store16_wt(void* p, int4v v) {
    asm volatile("global_store_dwordx4 %0, %1, off sc0 sc1" :: "v"(p), "v"(v) : "memory");
}
static __device__ __forceinline__ void store4_wt(void* p, float v) {
    asm volatile("global_store_dword %0, %1, off sc0 sc1" :: "v"(p), "v"(v) : "memory");
}
static __device__ __forceinline__ void storeu4_wt(void* p, unsigned int v) {
    asm volatile("global_store_dword %0, %1, off sc0 sc1" :: "v"(p), "v"(v) : "memory");
}
// coherence-point loads (bypass L1+L2): always fresh, no acquire-inv needed.
static __device__ __forceinline__ int4v load16_nc(const void* p) {
    int4v v;   // no internal waitcnt — caller fences
    asm volatile("global_load_dwordx4 %0, %1, off sc0 sc1" : "=v"(v) : "v"(p) : "memory");
    return v;
}
static __device__ __forceinline__ float load4_nc(const void* p) {
    float v;   // no internal waitcnt — drained by the next poll fence
    asm volatile("global_load_dword %0, %1, off sc0 sc1" : "=v"(v) : "v"(p) : "memory");
    return v;
}
static __device__ __forceinline__ float load4_ncw(const void* p) {
    float v;
    asm volatile("global_load_dword %0, %1, off sc0 sc1\n\ts_waitcnt vmcnt(0)"
                 : "=v"(v) : "v"(p) : "memory");
    return v;
}
// a 16B chunk is valid iff no dword equals the poison pair. Producers write
// dword-paired values (single dword stores = atomic), so a dword is either
// full-poison or full-data — never torn.
static __device__ __forceinline__ int clean4(int4v c) {
    return (c[0] != (int)POISON) & (c[1] != (int)POISON) &
           (c[2] != (int)POISON) & (c[3] != (int)POISON);
}

// Persistent LSTM decoder. 8 groups x 32 blocks (static grouping). Group g owns
// batches [16g,16g+16); block rb owns dims [32rb,32rb+32) => 128 gate rows
// (8 n-tiles). W' = W_hh + W_ih[:,0](x)W_lin, hi-bf16, in registers. Wave w
// owns K-eighth [128w,128w+128) and ALL 8 n-tiles.
//
// R11 == R9 (proven: flagless data-polling, depth-4 h ring, poison sentinel,
// pre-issued pbuf read; pre-issued h-polls RETIRED after R8/R10 NaN'd twice)
// + two orthogonal-class deltas:
//  - RAW POST-C BARRIER: __syncthreads() emits s_waitcnt vmcnt(0) before
//    s_barrier, so R9 paid the phase-C store ack (~300-500cy) serially at the
//    barrier. The protocol's drain point is the PHASE-A poll vmcnt(0) (every
//    certificate cites it), so the post-C sync only needs LDS ordering:
//    lgkmcnt(0) + raw s_barrier + sched_barrier(0). The store ack now
//    overlaps the poll RTT.
//  - FAST TANH (tanhf_fast above): shortens the serial Dlds->publish chain.
// Failure signatures are disjoint: NaN/hang -> barrier delta; finite absmax
// degradation -> tanh delta.
__global__ __launch_bounds__(NTHR, 2) void decoder_kernel(
    const float* __restrict__ hidden0, const float* __restrict__ cell0,
    const float* __restrict__ Wih,     const float* __restrict__ Whh,
    const float* __restrict__ bih,     const float* __restrict__ bhh,
    const float* __restrict__ Wlin,    const float* __restrict__ blin,
    float* __restrict__ out,           float* __restrict__ ws)
{
    __shared__ __align__(16) float Dlds[8][8][16][20];   // 80 KB: [kk][ntl][n][m+pad4]
    __shared__ float s0_lds[MPG];

    const int blk  = blockIdx.x;
    const int g    = blk >> 5;          // group 0..7
    const int rb   = blk & 31;          // block in group 0..31
    const int tid  = threadIdx.x;
    const int lane = tid & 63;
    const int wave = tid >> 6;          // 8 waves: wave = K-eighth
    const int l15  = lane & 15;
    const int q    = lane >> 4;

    // ws: flags 8 groups x 64 uints | h ring 1MB (4 slots) | pbuf ring 128 KB
    unsigned int*   flags = (unsigned int*)ws + g * 64;            // 32 used
    unsigned short* hbuf  = (unsigned short*)((char*)ws + 4096);   // [4][G][GRP_SHORTS]
    float*          pbuf  = (float*)((char*)ws + 4096
                             + (size_t)HSLOTS * GRP_STRIDE * 2);   // [4][G][MPG][64]

    // ---- W' hi-bf16 B-fragments in registers: 8 n-tiles x K/8 = 32 frags ----
    bf16x8 w_hi[8][4];
    #pragma unroll
    for (int ntl = 0; ntl < 8; ++ntl) {
        const int gate = ntl >> 1;
        const int row  = gate * H + rb * DPB + (ntl & 1) * 16 + l15;
        const float* wrow  = Whh + (size_t)row * H;
        const float  wih0r = Wih[row * 2];
        #pragma unroll
        for (int kt = 0; kt < 4; ++kt) {
            const int k0 = wave * 128 + kt * 32 + q * 8;
            #pragma unroll
            for (int j = 0; j < 8; ++j) {
                float w = wrow[k0 + j] + wih0r * Wlin[k0 + j];
                w_hi[ntl][kt][j] = (short)bf16_rne(w);
            }
        }
    }

    // ---- pointwise-thread constants (R5 mapping): pm=bq*4+q, pj=nhi*16+l15 ----
    const int bq    = wave >> 1;              // batch quad 0..3
    const int nhi   = wave & 1;               // dim half 0..1
    const int pm    = bq * 4 + q;             // batch in group 0..15
    const int pj    = nhi * 16 + l15;         // dim within block 0..31
    const int bglob = g * MPG + pm;
    const int kdim  = rb * DPB + pj;
    const float bl  = blin[0];
    float bias_p[4], bias0_p[4], wih0_p[4];
    #pragma unroll
    for (int gt = 0; gt < 4; ++gt) {
        int r2 = gt * H + kdim;
        float b0 = bih[r2] + bhh[r2];
        float w0 = Wih[r2 * 2];
        bias0_p[gt] = b0;
        wih0_p[gt]  = w0;
        bias_p[gt]  = b0 + Wih[r2 * 2 + 1] + w0 * bl;   // folded bias (t>=1)
    }
    float cstate = cell0[(size_t)bglob * H + kdim];
    const float wlin_p = Wlin[kdim];

    // h addressing: chunk layout short index within a (slot,group) region
    const size_t hoff = (size_t)rb * 512 + (pj >> 3) * 128 + pm * 8 + (pj & 7);
    unsigned short* hgrp   = hbuf + (size_t)g * GRP_SHORTS;    // slot 0 of my group
    unsigned short* hpairb = hgrp + hoff;                      // my pair addr (even lanes)
    unsigned short* mychk  = hgrp + (size_t)rb * 512;          // my 1KB chunk, slot 0

    const int4v pois = { (int)POISON, (int)POISON, (int)POISON, (int)POISON };

    // ---- preamble: poison own chunk in ALL 4 slots (before any h0 publish) ----
    if (lane < 8) {
        #pragma unroll
        for (int s = 0; s < HSLOTS; ++s)
            store16_wt((char*)(mychk + (size_t)s * GRP_STRIDE) + wave * 128 + lane * 16,
                       pois);
    }

    // ---- s0[m] = Wlin . h0[m]  (t=0 rank-1 correction; old thread mapping) ----
    {
        const int pm_o = tid >> 5, pj_o = tid & 31;
        const float* hp = hidden0 + (size_t)(g * MPG + pm_o) * H + pj_o * 32;
        const float* wp = Wlin + pj_o * 32;
        float s = 0.f;
        #pragma unroll 4
        for (int kk = 0; kk < 32; kk += 4) {
            float4 hv = *(const float4*)(hp + kk);
            float4 wv = *(const float4*)(wp + kk);
            s += hv.x * wv.x + hv.y * wv.y + hv.z * wv.z + hv.w * wv.w;
        }
        s += __shfl_xor(s, 1); s += __shfl_xor(s, 2);
        s += __shfl_xor(s, 4); s += __shfl_xor(s, 8); s += __shfl_xor(s, 16);
        if (pj_o == 0) s0_lds[pm_o] = s;
    }

    // one-time flag round: all poisons committed before ANY h0 store issues
    asm volatile("s_waitcnt vmcnt(0)" ::: "memory");
    __syncthreads();
    if (tid == 0)
        __hip_atomic_store(&flags[rb], 1u, __ATOMIC_RELAXED, __HIP_MEMORY_SCOPE_AGENT);
    if (wave == 0) {
        for (int spin = 0; spin < SPIN_MAX; ++spin) {
            unsigned int v = __hip_atomic_load(&flags[lane & 31], __ATOMIC_RELAXED,
                                               __HIP_MEMORY_SCOPE_AGENT);
            if (__all((int)(v >= 1u))) break;
        }
    }
    __syncthreads();

    // ---- h0 publish into slot 0: paired-dword, fire-and-forget ----
    {
        float v0 = hidden0[(size_t)bglob * H + kdim];
        unsigned int hs = bf16_rne(v0);
        unsigned int pw = (unsigned int)__shfl_xor((int)hs, 1);
        if (!(lane & 1))
            storeu4_wt(hpairb, (hs & 0xFFFFu) | (pw << 16));
    }

    float pv = 0.f;   // pre-issued pbuf partial (wave1), drained by poll fence

    for (int t = 0; t < T; ++t) {
        // ---- phase A: DATA-POLL this wave's 4 chunks of slot t&3 ----
        const char* hsrc = (const char*)(hgrp + (size_t)(t & 3) * GRP_STRIDE)
                         + wave * 4096 + lane * 16;
        int4v a0, a1, a2, a3;
        for (int spin = 0; spin < SPIN_MAX; ++spin) {
            a0 = load16_nc(hsrc);
            a1 = load16_nc(hsrc + 1024);
            a2 = load16_nc(hsrc + 2048);
            a3 = load16_nc(hsrc + 3072);
            // drain point: commits all of MY prior stores (poison/h/pbuf) and
            // completes these loads + the pre-issued pv load
            asm volatile("s_waitcnt vmcnt(0)"
                         : "+v"(a0), "+v"(a1), "+v"(a2), "+v"(a3), "+v"(pv));
            if (__all(clean4(a0) & clean4(a1) & clean4(a2) & clean4(a3))) break;
        }
        if (wave == 1 && rb < MPG && t >= 3) {
            // batch m = rb: step t-3's 64 partials (pre-issued last phase C)
            float v = pv;
            v += __shfl_xor(v, 1); v += __shfl_xor(v, 2); v += __shfl_xor(v, 4);
            v += __shfl_xor(v, 8); v += __shfl_xor(v, 16); v += __shfl_xor(v, 32);
            if (lane == 0) out[(size_t)(g * MPG + rb) * T + (t - 3)] = v + bl;
        }

        // ---- phase B: MFMA. wave w: 8 n-tiles x 16 batches x K/8 ----
        bf16x8 a[4];
        a[0] = __builtin_bit_cast(bf16x8, a0);
        a[1] = __builtin_bit_cast(bf16x8, a1);
        a[2] = __builtin_bit_cast(bf16x8, a2);
        a[3] = __builtin_bit_cast(bf16x8, a3);
        floatx4 acc[8];
        #pragma unroll
        for (int ntl = 0; ntl < 8; ++ntl) acc[ntl] = (floatx4){0.f, 0.f, 0.f, 0.f};
        #pragma unroll
        for (int kt = 0; kt < 4; ++kt) {
            #pragma unroll
            for (int ntl = 0; ntl < 8; ++ntl)
                acc[ntl] = __builtin_amdgcn_mfma_f32_16x16x32_bf16(a[kt], w_hi[ntl][kt], acc[ntl], 0, 0, 0);
        }
        #pragma unroll
        for (int ntl = 0; ntl < 8; ++ntl)
            *(floatx4*)&Dlds[wave][ntl][l15][q * 4] = acc[ntl];
        __syncthreads();   // post-B: Dlds complete (implicit vmcnt here is ~free:
                           // phase-A already drained; lgkmcnt covers ds_writes)

        // ---- phase C (R9 order: poison first, compute, publish, pbuf) ----
        // re-arm: poison my chunk of slot (t+3)&3 == (t-1)&3 (peers' reads of
        // it are certified complete by the merged post-B observations of h_t)
        if (lane < 8)
            store16_wt((char*)(mychk + (size_t)((t + 3) & 3) * GRP_STRIDE)
                       + wave * 128 + lane * 16, pois);
        {
            // b128 kk-sum: gate q's chain for dims pj, batches bq*4..+3
            const float* rbase = &Dlds[0][q * 2 + nhi][l15][bq * 4];
            floatx4 S = *(const floatx4*)rbase;
            #pragma unroll
            for (int kk = 1; kk < 8; ++kk)
                S = S + *(const floatx4*)(rbase + kk * 2560);   // kk stride 8*16*20

            // 4x4 transpose across lane quads: gg[i] = gate i, batch bq*4+q
            float a4[4] = {S[0], S[1], S[2], S[3]};
            float cc[4], gg[4];
            #pragma unroll
            for (int j = 0; j < 4; ++j) {
                float tv = __shfl_xor(a4[j ^ 1], 16);
                cc[j] = ((j ^ q) & 1) ? tv : a4[j];
            }
            #pragma unroll
            for (int j = 0; j < 4; ++j) {
                float tv = __shfl_xor(cc[j ^ 2], 32);
                gg[j] = ((j ^ q) & 2) ? tv : cc[j];
            }

            float gv[4];
            if (t == 0) {
                float s0 = s0_lds[pm];
                #pragma unroll
                for (int gt = 0; gt < 4; ++gt) gv[gt] = gg[gt] + bias0_p[gt] - wih0_p[gt] * s0;
            } else {
                #pragma unroll
                for (int gt = 0; gt < 4; ++gt) gv[gt] = gg[gt] + bias_p[gt];
            }
            float ig  = sigmoidf_(gv[0]);
            float fg  = sigmoidf_(gv[1]);
            float gt_ = tanhf_fast(gv[2]);
            float og  = sigmoidf_(gv[3]);
            cstate = fg * cstate + ig * gt_;
            float hnew = og * tanhf_fast(cstate);

            // h publish into slot (t+1)&3: paired-dword (atomic, never torn),
            // fire-and-forget — consumers' data-polls detect arrival directly
            unsigned int hs = bf16_rne(hnew);
            unsigned int pw = (unsigned int)__shfl_xor((int)hs, 1);
            if (!(lane & 1))
                storeu4_wt(hpairb + (size_t)((t + 1) & 3) * GRP_STRIDE,
                           (hs & 0xFFFFu) | (pw << 16));

            // po partial per (batch, dim-half): reduce over 16 dim lanes
            float po = wlin_p * hnew;
            po += __shfl_xor(po, 1); po += __shfl_xor(po, 2);
            po += __shfl_xor(po, 4); po += __shfl_xor(po, 8);
            if (l15 == 0)
                store4_wt(pbuf + (size_t)(((t & 3) * GROUPS + g) * MPG + pm) * 64
                          + nhi * 32 + rb, po);
        }

        // ---- pre-issue step t+1's pbuf read (wave1; slot (t-2)&3, certified
        //      committed by this step's post-B all-32 merge) — R9-proven ----
        if (wave == 1 && rb < MPG && t >= 2 && t < T - 1) {
            const float* pr = pbuf + (size_t)((((t - 2) & 3) * GROUPS + g) * MPG + rb) * 64;
            pv = load4_nc(pr + lane);
        }

        // ---- post-C sync: RAW barrier — LDS ordering only. The phase-C WT
        //      stores stay in flight and ack during the next phase-A poll RTT
        //      (the protocol's drain point) instead of serially here. ----
        asm volatile("s_waitcnt lgkmcnt(0)" ::: "memory");
        __builtin_amdgcn_s_barrier();
        __builtin_amdgcn_sched_barrier(0);
    }

    // ---- epilogue: one flag round orders final pbuf commits, then T-3..T-1 ----
    asm volatile("s_waitcnt vmcnt(0)" ::: "memory");
    __syncthreads();
    if (tid == 0)
        __hip_atomic_store(&flags[rb], 2u, __ATOMIC_RELAXED, __HIP_MEMORY_SCOPE_AGENT);
    if (wave == 1 && rb < MPG) {
        for (int spin = 0; spin < SPIN_MAX; ++spin) {
            unsigned int v = __hip_atomic_load(&flags[lane & 31], __ATOMIC_RELAXED,
                                               __HIP_MEMORY_SCOPE_AGENT);
            if (__all((int)(v >= 2u))) break;
        }
        for (int tt = T - 3; tt < T; ++tt) {
            const float* pr = pbuf + (size_t)(((tt & 3) * GROUPS + g) * MPG + rb) * 64;
            float v = load4_ncw(pr + lane);
            v += __shfl_xor(v, 1); v += __shfl_xor(v, 2); v += __shfl_xor(v, 4);
            v += __shfl_xor(v, 8); v += __shfl_xor(v, 16); v += __shfl_xor(v, 32);
            if (lane == 0) out[(size_t)(g * MPG + rb) * T + tt] = v + bl;
        }
    }
}

extern "C" void kernel_launch(void* const* d_in, const int* in_sizes, int n_in,
                              void* d_out, int out_size, void* d_ws, size_t ws_size,
                              hipStream_t stream) {
    const float* hidden0 = (const float*)d_in[0];
    const float* cell0   = (const float*)d_in[1];
    const float* Wih     = (const float*)d_in[2];
    const float* Whh     = (const float*)d_in[3];
    const float* bih     = (const float*)d_in[4];
    const float* bhh     = (const float*)d_in[5];
    const float* Wlin    = (const float*)d_in[6];
    const float* blin    = (const float*)d_in[7];
    float* out = (float*)d_out;
    float* ws  = (float*)d_ws;

    // zero the preamble/epilogue flags
    hipMemsetAsync(d_ws, 0, 4096, stream);

    void* args[] = { &hidden0, &cell0, &Wih, &Whh, &bih, &bhh, &Wlin, &blin,
                     &out, &ws };
    hipLaunchCooperativeKernel((const void*)decoder_kernel,
                               dim3(GROUPS * BPG), dim3(NTHR), args, 0, stream);
}